// Round 8
// baseline (386.101 us; speedup 1.0000x reference)
//
#include <hip/hip_runtime.h>
#include <cmath>
#include <cstdint>

typedef __bf16 bf16;
typedef bf16 bf16x4 __attribute__((ext_vector_type(4)));
typedef bf16 bf16x8 __attribute__((ext_vector_type(8)));
typedef float f32x4 __attribute__((ext_vector_type(4)));
typedef unsigned int u32;
typedef u32 u32x4 __attribute__((ext_vector_type(4)));

#define EPS 1e-5f

__device__ __forceinline__ float clipf(float v) {
    return fminf(fmaxf(v, -10000.0f), 10000.0f);
}
__device__ __forceinline__ float fin0(float v) { return isfinite(v) ? v : 0.0f; }

__device__ __forceinline__ void async_copy16(void* lds, const void* g) {
    __builtin_amdgcn_global_load_lds((__attribute__((address_space(1))) void*)(void*)g,
                                     (__attribute__((address_space(3))) void*)lds,
                                     16, 0, 0);
}

// ================= prep: all weight converts + input rmsnorm, one dispatch =================
// flat grid 15872 blocks x 256 thr.
__global__ __launch_bounds__(256) void prep(const float* __restrict__ wq, const float* __restrict__ wk,
                                            const float* __restrict__ wv, const float* __restrict__ wo,
                                            bf16* __restrict__ Wq, bf16* __restrict__ Wk,
                                            bf16* __restrict__ Wv, bf16* __restrict__ Wo,
                                            const float* __restrict__ w1, const float* __restrict__ w3,
                                            bf16* __restrict__ W1p, bf16* __restrict__ W3p,
                                            const float* __restrict__ w2, bf16* __restrict__ W2p,
                                            const float* __restrict__ x, const float* __restrict__ snw,
                                            bf16* __restrict__ xn) {
    const int bid = blockIdx.x, t = threadIdx.x;
    if (bid < 4096) {
        int z = bid >> 10, r = bid & 1023;
        const float* in = (z == 0) ? wq : (z == 1) ? wk : (z == 2) ? wv : wo;
        bf16* out = (z == 0) ? Wq : (z == 1) ? Wk : (z == 2) ? Wv : Wo;
        f32x4 v = ((const f32x4*)(in + (size_t)r * 1024))[t];
        bf16x4 o = {(bf16)v[0], (bf16)v[1], (bf16)v[2], (bf16)v[3]};
        ((bf16x4*)(out + (size_t)r * 1024))[t] = o;
    } else if (bid < 10752) {
        int b2 = bid - 4096;
        int which = b2 >= 3328;
        int r = b2 - (which ? 3328 : 0);
        const float* in = which ? w3 : w1;
        bf16* out = which ? W3p : W1p;
        bf16x4 o = {(bf16)0.f, (bf16)0.f, (bf16)0.f, (bf16)0.f};
        if (r < 3280) {
            f32x4 v = ((const f32x4*)(in + (size_t)r * 1024))[t];
            o[0] = (bf16)v[0]; o[1] = (bf16)v[1]; o[2] = (bf16)v[2]; o[3] = (bf16)v[3];
        }
        ((bf16x4*)(out + (size_t)r * 1024))[t] = o;
    } else if (bid < 11776) {
        int r = bid - 10752;
        for (int c4 = t * 4; c4 < 3328; c4 += 1024) {
            bf16x4 o = {(bf16)0.f, (bf16)0.f, (bf16)0.f, (bf16)0.f};
            if (c4 + 3 < 3280) {
                f32x4 v = *(const f32x4*)(w2 + (size_t)r * 3280 + c4);
                o[0] = (bf16)v[0]; o[1] = (bf16)v[1]; o[2] = (bf16)v[2]; o[3] = (bf16)v[3];
            } else {
                #pragma unroll
                for (int j = 0; j < 4; ++j)
                    if (c4 + j < 3280) o[j] = (bf16)w2[(size_t)r * 3280 + c4 + j];
            }
            *(bf16x4*)(W2p + (size_t)r * 3328 + c4) = o;
        }
    } else {
        __shared__ float sred[4];
        int row = bid - 11776;
        f32x4 xv = ((const f32x4*)(x + (size_t)row * 1024))[t];
        f32x4 cv;
        cv[0] = clipf(xv[0]); cv[1] = clipf(xv[1]); cv[2] = clipf(xv[2]); cv[3] = clipf(xv[3]);
        float ss = cv[0]*cv[0] + cv[1]*cv[1] + cv[2]*cv[2] + cv[3]*cv[3];
        #pragma unroll
        for (int off = 32; off >= 1; off >>= 1) ss += __shfl_xor(ss, off, 64);
        if ((t & 63) == 0) sred[t >> 6] = ss;
        __syncthreads();
        float tot = sred[0] + sred[1] + sred[2] + sred[3];
        float rms = sqrtf(fmaxf(tot * (1.0f / 1024.0f), EPS) + EPS);
        f32x4 wv_ = ((const f32x4*)snw)[t];
        bf16x4 o;
        o[0] = (bf16)fin0(cv[0] / rms * wv_[0]);
        o[1] = (bf16)fin0(cv[1] / rms * wv_[1]);
        o[2] = (bf16)fin0(cv[2] / rms * wv_[2]);
        o[3] = (bf16)fin0(cv[3] / rms * wv_[3]);
        *(bf16x4*)(xn + (size_t)row * 1024 + t * 4) = o;
    }
}

// ================= QKV GEMM (dbuf), fused head-rmsnorm (q,k), vT epilogue =================
// grid (32, 8, 3), block 256.
__global__ __launch_bounds__(256) void gemm_qkv(const bf16* __restrict__ A,
                                                const bf16* __restrict__ B0,
                                                const bf16* __restrict__ B1,
                                                const bf16* __restrict__ B2,
                                                const float* __restrict__ g0,
                                                const float* __restrict__ g1,
                                                const float* __restrict__ g2,
                                                const float* __restrict__ qnw,
                                                const float* __restrict__ knw,
                                                bf16* __restrict__ C0,
                                                bf16* __restrict__ C1,
                                                bf16* __restrict__ VT) {
    const int z = blockIdx.z;
    const bf16* B = (z == 0) ? B0 : (z == 1) ? B1 : B2;
    const float* bias = (z == 0) ? g0 : (z == 1) ? g1 : g2;
    const float* hw = (z == 0) ? qnw : knw;

    __shared__ __align__(16) bf16 sA[2][128 * 32];
    __shared__ __align__(16) bf16 sB[2][128 * 32];
    const int tid = threadIdx.x;
    const int w = tid >> 6, lane = tid & 63;
    const int m0 = blockIdx.x * 128;
    const int n0 = blockIdx.y * 128;
    const int mwo = (w >> 1) * 64, nwo = (w & 1) * 64;
    const int r16 = lane & 15, quad = lane >> 4;
    const int kreg = quad * 8;
    const int K = 1024, N = 1024;

    f32x4 zero = {0.f, 0.f, 0.f, 0.f};
    f32x4 acc[4][4];
    #pragma unroll
    for (int i = 0; i < 4; ++i)
        #pragma unroll
        for (int j = 0; j < 4; ++j) acc[i][j] = zero;

    const int c0 = tid, c1 = tid + 256;
    const int am0 = c0 >> 2, ak0 = (c0 & 3) << 3;
    const int am1 = c1 >> 2, ak1 = (c1 & 3) << 3;

    {
        async_copy16(&sA[0][c0 * 8], &A[(size_t)(m0 + am0) * K + ak0]);
        async_copy16(&sA[0][c1 * 8], &A[(size_t)(m0 + am1) * K + ak1]);
        async_copy16(&sB[0][c0 * 8], &B[(size_t)(n0 + am0) * K + ak0]);
        async_copy16(&sB[0][c1 * 8], &B[(size_t)(n0 + am1) * K + ak1]);
    }
    for (int kt = 0; kt < 32; ++kt) {
        __syncthreads();
        const int cur = kt & 1, nxt = cur ^ 1;
        if (kt + 1 < 32) {
            const int kb = (kt + 1) << 5;
            async_copy16(&sA[nxt][c0 * 8], &A[(size_t)(m0 + am0) * K + kb + ak0]);
            async_copy16(&sA[nxt][c1 * 8], &A[(size_t)(m0 + am1) * K + kb + ak1]);
            async_copy16(&sB[nxt][c0 * 8], &B[(size_t)(n0 + am0) * K + kb + ak0]);
            async_copy16(&sB[nxt][c1 * 8], &B[(size_t)(n0 + am1) * K + kb + ak1]);
        }
        bf16x8 af[4], bfr[4];
        #pragma unroll
        for (int i = 0; i < 4; ++i) {
            af[i]  = *(const bf16x8*)&sA[cur][(mwo + i * 16 + r16) * 32 + kreg];
            bfr[i] = *(const bf16x8*)&sB[cur][(nwo + i * 16 + r16) * 32 + kreg];
        }
        #pragma unroll
        for (int mi = 0; mi < 4; ++mi)
            #pragma unroll
            for (int ni = 0; ni < 4; ++ni)
                acc[mi][ni] = __builtin_amdgcn_mfma_f32_16x16x32_bf16(af[mi], bfr[ni], acc[mi][ni], 0, 0, 0);
    }

    float bv[4];
    #pragma unroll
    for (int ni = 0; ni < 4; ++ni) bv[ni] = bias[n0 + nwo + ni * 16 + r16];

    if (z < 2) {
        bf16* C = (z == 0) ? C0 : C1;
        float nwv[4];
        #pragma unroll
        for (int ni = 0; ni < 4; ++ni) nwv[ni] = hw[ni * 16 + r16];
        #pragma unroll
        for (int mi = 0; mi < 4; ++mi) {
            #pragma unroll
            for (int r = 0; r < 4; ++r) {
                float v[4], ss = 0.0f;
                #pragma unroll
                for (int ni = 0; ni < 4; ++ni) {
                    v[ni] = clipf(acc[mi][ni][r] + bv[ni]);
                    ss += v[ni] * v[ni];
                }
                ss += __shfl_xor(ss, 1, 64);
                ss += __shfl_xor(ss, 2, 64);
                ss += __shfl_xor(ss, 4, 64);
                ss += __shfl_xor(ss, 8, 64);
                float rms = sqrtf(fmaxf(ss * (1.0f / 64.0f), EPS) + EPS);
                int row = m0 + mwo + mi * 16 + quad * 4 + r;
                #pragma unroll
                for (int ni = 0; ni < 4; ++ni) {
                    int col = n0 + nwo + ni * 16 + r16;
                    C[(size_t)row * N + col] = (bf16)fin0(v[ni] / rms * nwv[ni]);
                }
            }
        }
    } else {
        const int b_ = m0 >> 10;
        const int tokbase = (m0 & 1023) + mwo;
        #pragma unroll
        for (int ni = 0; ni < 4; ++ni) {
            int col = n0 + nwo + ni * 16 + r16;
            int h_ = col >> 6, hd = col & 63;
            bf16* dst = VT + (((size_t)b_ * 16 + h_) * 64 + hd) * 1024;
            #pragma unroll
            for (int mi = 0; mi < 4; ++mi) {
                bf16x4 pack;
                #pragma unroll
                for (int r = 0; r < 4; ++r) pack[r] = (bf16)(acc[mi][ni][r] + bv[ni]);
                *(bf16x4*)&dst[tokbase + mi * 16 + quad * 4] = pack;
            }
        }
    }
}

// ================= windowed causal flash attention, 128 q-rows/block =================
// grid: (L/128, H, B), block 512 (8 waves = 2 q-subtiles x 4). q/k: (B,L,H,64); vt: (B,H,64,L).
// K/V staged once per K-tile, shared by both q-subtiles (stagings/hb: 72 -> 42).
__global__ __launch_bounds__(512) void attn_win(const bf16* __restrict__ q,
                                                const bf16* __restrict__ k,
                                                const bf16* __restrict__ vt,
                                                const int* __restrict__ winp,
                                                bf16* __restrict__ o) {
    __shared__ __align__(16) bf16 sQ[128 * 64];
    __shared__ __align__(16) bf16 sK[64 * 64];
    __shared__ __align__(16) bf16 sVt[64 * 80];
    __shared__ __align__(16) bf16 sP[128 * 64];
    const int tid = threadIdx.x, w = tid >> 6, lane = tid & 63;
    const int h = blockIdx.y, b = blockIdx.z;
    const int q0 = blockIdx.x * 128;                 // block's first q row
    const int qbase = (w >> 2) * 64 + (w & 3) * 16;  // wave's first q row within block
    const int win = *winp;
    const float scale = 0.125f;
    const int r16 = lane & 15, quad = lane >> 4;

    // stage Q (128 x 64): 2 async copies per thread
    {
        int qr0 = tid >> 3, col0 = (tid & 7) * 8;
        async_copy16(&sQ[tid * 8], &q[(((size_t)b * 1024 + q0 + qr0) * 16 + h) * 64 + col0]);
        int c1 = tid + 512;
        int qr1 = c1 >> 3, col1 = (c1 & 7) * 8;
        async_copy16(&sQ[c1 * 8], &q[(((size_t)b * 1024 + q0 + qr1) * 16 + h) * 64 + col1]);
    }
    __syncthreads();
    bf16x8 aq0 = *(const bf16x8*)&sQ[(qbase + r16) * 64 + quad * 8];
    bf16x8 aq1 = *(const bf16x8*)&sQ[(qbase + r16) * 64 + 32 + quad * 8];

    float M[4], Lr[4];
    f32x4 zero = {0.f, 0.f, 0.f, 0.f};
    f32x4 accO[4];
    #pragma unroll
    for (int r = 0; r < 4; ++r) { M[r] = -INFINITY; Lr[r] = 0.0f; }
    #pragma unroll
    for (int nf = 0; nf < 4; ++nf) accO[nf] = zero;

    int lo = q0 - (win - 1); if (lo < 0) lo = 0;
    const int kt0 = lo >> 6;
    const int kthi = (q0 + 64) >> 6;                 // last tile needed by upper subtile
    const bf16* vth = vt + ((size_t)b * 16 + h) * 64 * 1024;

    for (int kt = kt0; kt <= kthi; ++kt) {
        __syncthreads();
        {
            int col0 = (tid & 7) * 8;
            async_copy16(&sK[tid * 8], &k[(((size_t)b * 1024 + kt * 64 + (tid >> 3)) * 16 + h) * 64 + col0]);
        }
        {
            int hd = tid >> 3, koff = (tid & 7) * 8;
            *(u32x4*)&sVt[hd * 80 + koff] = *(const u32x4*)&vth[(size_t)hd * 1024 + kt * 64 + koff];
        }
        __syncthreads();

        f32x4 sf[4];
        #pragma unroll
        for (int nf = 0; nf < 4; ++nf) {
            bf16x8 bk0 = *(const bf16x8*)&sK[(nf * 16 + r16) * 64 + quad * 8];
            bf16x8 bk1 = *(const bf16x8*)&sK[(nf * 16 + r16) * 64 + 32 + quad * 8];
            f32x4 accS = zero;
            accS = __builtin_amdgcn_mfma_f32_16x16x32_bf16(aq0, bk0, accS, 0, 0, 0);
            accS = __builtin_amdgcn_mfma_f32_16x16x32_bf16(aq1, bk1, accS, 0, 0, 0);
            sf[nf] = accS;
        }

        #pragma unroll
        for (int r = 0; r < 4; ++r) {
            int i = q0 + qbase + quad * 4 + r;
            float p[4];
            float rowmax = -INFINITY;
            #pragma unroll
            for (int nf = 0; nf < 4; ++nf) {
                int j = kt * 64 + nf * 16 + r16;
                bool ok = (j <= i) && (i - j < win);
                float sv = ok ? sf[nf][r] * scale : -INFINITY;
                p[nf] = sv;
                rowmax = fmaxf(rowmax, sv);
            }
            #pragma unroll
            for (int off = 1; off < 16; off <<= 1)
                rowmax = fmaxf(rowmax, __shfl_xor(rowmax, off, 64));
            float mnew = fmaxf(M[r], rowmax);
            float alpha = (mnew == M[r]) ? 1.0f : __expf(M[r] - mnew);
            float rs = 0.0f;
            #pragma unroll
            for (int nf = 0; nf < 4; ++nf) {
                float pv = (p[nf] == -INFINITY) ? 0.0f : __expf(p[nf] - mnew);
                rs += pv;
                sP[(qbase + quad * 4 + r) * 64 + nf * 16 + r16] = (bf16)pv;
            }
            #pragma unroll
            for (int off = 1; off < 16; off <<= 1) rs += __shfl_xor(rs, off, 64);
            Lr[r] = Lr[r] * alpha + rs;
            M[r] = mnew;
            #pragma unroll
            for (int nf = 0; nf < 4; ++nf) accO[nf][r] = accO[nf][r] * alpha;
        }
        __syncthreads();

        bf16x8 ap0 = *(const bf16x8*)&sP[(qbase + r16) * 64 + quad * 8];
        bf16x8 ap1 = *(const bf16x8*)&sP[(qbase + r16) * 64 + 32 + quad * 8];
        #pragma unroll
        for (int nf = 0; nf < 4; ++nf) {
            bf16x8 bv0 = *(const bf16x8*)&sVt[(nf * 16 + r16) * 80 + quad * 8];
            bf16x8 bv1 = *(const bf16x8*)&sVt[(nf * 16 + r16) * 80 + 32 + quad * 8];
            accO[nf] = __builtin_amdgcn_mfma_f32_16x16x32_bf16(ap0, bv0, accO[nf], 0, 0, 0);
            accO[nf] = __builtin_amdgcn_mfma_f32_16x16x32_bf16(ap1, bv1, accO[nf], 0, 0, 0);
        }
    }

    #pragma unroll
    for (int r = 0; r < 4; ++r) {
        float inv = (Lr[r] > 0.0f) ? 1.0f / Lr[r] : 0.0f;
        int row = q0 + qbase + quad * 4 + r;
        #pragma unroll
        for (int nf = 0; nf < 4; ++nf) {
            float ov = fin0(accO[nf][r] * inv);
            o[(((size_t)b * 1024 + row) * 16 + h) * 64 + nf * 16 + r16] = (bf16)ov;
        }
    }
}

// ================= non-split 64x128-tile GEMM -> f32 (no bias) =================
// C[M,1024] = A[M,K] @ B[1024,K]^T. grid (M/64, 8), block 256 (4 waves, 32x64/wave).
__global__ __launch_bounds__(256) void gemm_nk(const bf16* __restrict__ A,
                                               const bf16* __restrict__ B,
                                               float* __restrict__ C, int K) {
    __shared__ __align__(16) bf16 sA[2][64 * 32];
    __shared__ __align__(16) bf16 sB[2][128 * 32];
    const int tid = threadIdx.x;
    const int w = tid >> 6, lane = tid & 63;
    const int m0 = blockIdx.x * 64, n0 = blockIdx.y * 128;
    const int mwo = (w >> 1) * 32, nwo = (w & 1) * 64;
    const int r16 = lane & 15, quad = lane >> 4, kreg = quad * 8;
    const int N = 1024;

    const int arow = tid >> 2, akoff = (tid & 3) << 3;
    const int c1 = tid + 256;
    const int brow1 = c1 >> 2, bkoff1 = (c1 & 3) << 3;

    f32x4 zero = {0.f, 0.f, 0.f, 0.f};
    f32x4 acc[2][4];
    #pragma unroll
    for (int i = 0; i < 2; ++i)
        #pragma unroll
        for (int j = 0; j < 4; ++j) acc[i][j] = zero;

    {
        async_copy16(&sA[0][tid * 8], &A[(size_t)(m0 + arow) * K + akoff]);
        async_copy16(&sB[0][tid * 8], &B[(size_t)(n0 + arow) * K + akoff]);
        async_copy16(&sB[0][c1 * 8], &B[(size_t)(n0 + brow1) * K + bkoff1]);
    }
    const int kIters = K >> 5;
    for (int kt = 0; kt < kIters; ++kt) {
        __syncthreads();
        const int cur = kt & 1, nxt = cur ^ 1;
        if (kt + 1 < kIters) {
            const int kb = (kt + 1) << 5;
            async_copy16(&sA[nxt][tid * 8], &A[(size_t)(m0 + arow) * K + kb + akoff]);
            async_copy16(&sB[nxt][tid * 8], &B[(size_t)(n0 + arow) * K + kb + akoff]);
            async_copy16(&sB[nxt][c1 * 8], &B[(size_t)(n0 + brow1) * K + kb + bkoff1]);
        }
        bf16x8 af[2], bfr[4];
        #pragma unroll
        for (int i = 0; i < 2; ++i)
            af[i] = *(const bf16x8*)&sA[cur][(mwo + i * 16 + r16) * 32 + kreg];
        #pragma unroll
        for (int i = 0; i < 4; ++i)
            bfr[i] = *(const bf16x8*)&sB[cur][(nwo + i * 16 + r16) * 32 + kreg];
        #pragma unroll
        for (int mi = 0; mi < 2; ++mi)
            #pragma unroll
            for (int ni = 0; ni < 4; ++ni)
                acc[mi][ni] = __builtin_amdgcn_mfma_f32_16x16x32_bf16(af[mi], bfr[ni], acc[mi][ni], 0, 0, 0);
    }

    #pragma unroll
    for (int mi = 0; mi < 2; ++mi)
        #pragma unroll
        for (int ni = 0; ni < 4; ++ni) {
            int col = n0 + nwo + ni * 16 + r16;
            #pragma unroll
            for (int r = 0; r < 4; ++r) {
                int row = m0 + mwo + mi * 16 + quad * 4 + r;
                C[(size_t)row * N + col] = acc[mi][ni][r];
            }
        }
}

// ================= resid+norm: a = p0+bias; h = x + rmsnorm(a, wpost); opt hn = rmsnorm(h, wnext) ====
template <bool EMIT>
__global__ __launch_bounds__(512) void resid_norm(const float* __restrict__ xres,
                                                  const float* __restrict__ p0,
                                                  const float* __restrict__ bias,
                                                  const float* __restrict__ wpost,
                                                  const float* __restrict__ wnext,
                                                  float* __restrict__ hout,
                                                  bf16* __restrict__ hnout) {
    __shared__ float sred[8];
    const int tid = threadIdx.x;
    const int grp = tid >> 8, t = tid & 255;
    const int w4 = (tid >> 6) & 3;
    for (int it = 0; it < 4; ++it) {
        int row = it * 1024 + blockIdx.x * 2 + grp;
        f32x4 a0 = ((const f32x4*)(p0 + (size_t)row * 1024))[t];
        f32x4 bv = ((const f32x4*)bias)[t];
        f32x4 af;
        af[0] = clipf(a0[0] + bv[0]);
        af[1] = clipf(a0[1] + bv[1]);
        af[2] = clipf(a0[2] + bv[2]);
        af[3] = clipf(a0[3] + bv[3]);
        float ss = af[0]*af[0] + af[1]*af[1] + af[2]*af[2] + af[3]*af[3];
        #pragma unroll
        for (int off = 32; off >= 1; off >>= 1) ss += __shfl_xor(ss, off, 64);
        __syncthreads();
        if ((tid & 63) == 0) sred[grp * 4 + w4] = ss;
        __syncthreads();
        float tot = sred[grp*4+0] + sred[grp*4+1] + sred[grp*4+2] + sred[grp*4+3];
        float rms1 = sqrtf(fmaxf(tot * (1.0f / 1024.0f), EPS) + EPS);
        f32x4 xv = ((const f32x4*)(xres + (size_t)row * 1024))[t];
        f32x4 wp = ((const f32x4*)wpost)[t];
        f32x4 hv;
        hv[0] = xv[0] + fin0(af[0] / rms1 * wp[0]);
        hv[1] = xv[1] + fin0(af[1] / rms1 * wp[1]);
        hv[2] = xv[2] + fin0(af[2] / rms1 * wp[2]);
        hv[3] = xv[3] + fin0(af[3] / rms1 * wp[3]);
        ((f32x4*)(hout + (size_t)row * 1024))[t] = hv;
        if (EMIT) {
            f32x4 cv;
            cv[0] = clipf(hv[0]); cv[1] = clipf(hv[1]); cv[2] = clipf(hv[2]); cv[3] = clipf(hv[3]);
            float ss2 = cv[0]*cv[0] + cv[1]*cv[1] + cv[2]*cv[2] + cv[3]*cv[3];
            #pragma unroll
            for (int off = 32; off >= 1; off >>= 1) ss2 += __shfl_xor(ss2, off, 64);
            __syncthreads();
            if ((tid & 63) == 0) sred[grp * 4 + w4] = ss2;
            __syncthreads();
            float tot2 = sred[grp*4+0] + sred[grp*4+1] + sred[grp*4+2] + sred[grp*4+3];
            float rms2 = sqrtf(fmaxf(tot2 * (1.0f / 1024.0f), EPS) + EPS);
            f32x4 wn = ((const f32x4*)wnext)[t];
            bf16x4 o;
            o[0] = (bf16)fin0(cv[0] / rms2 * wn[0]);
            o[1] = (bf16)fin0(cv[1] / rms2 * wn[1]);
            o[2] = (bf16)fin0(cv[2] / rms2 * wn[2]);
            o[3] = (bf16)fin0(cv[3] / rms2 * wn[3]);
            *(bf16x4*)(hnout + (size_t)row * 1024 + t * 4) = o;
        }
    }
}

// ================= fused FFN1, 128x64 tile, occupancy-tuned: g = silu(A@W1^T+b1)*(A@W3^T+b3) ====
// grid (32, 52), block 512 (8 waves: mhalf = w>>2, nq = w&3; per-wave 64x16 per stream).
// acc = 8 f32x4 = 32 regs -> target 6 waves/SIMD (3 blocks/CU). LDS 2x16KB = 32KB.
__global__ __launch_bounds__(512, 6) void gemm_ffn1(const bf16* __restrict__ A,
                                                    const bf16* __restrict__ B1,
                                                    const bf16* __restrict__ B3,
                                                    const float* __restrict__ b1,
                                                    const float* __restrict__ b3,
                                                    bf16* __restrict__ G) {
    __shared__ __align__(16) bf16 sA[2][128 * 32];
    __shared__ __align__(16) bf16 sB1[2][64 * 32];
    __shared__ __align__(16) bf16 sB3[2][64 * 32];
    const int tid = threadIdx.x;
    const int w = tid >> 6, lane = tid & 63;
    const int m0 = blockIdx.x * 128;
    const int n0 = blockIdx.y * 64;
    const int mwo = (w >> 2) * 64, nwo = (w & 3) * 16;
    const int r16 = lane & 15, quad = lane >> 4;
    const int kreg = quad * 8;
    const int K = 1024, N = 3328;

    f32x4 zero = {0.f, 0.f, 0.f, 0.f};
    f32x4 acc1[4], acc3[4];
    #pragma unroll
    for (int i = 0; i < 4; ++i) { acc1[i] = zero; acc3[i] = zero; }

    const int arow = tid >> 2, akoff = (tid & 3) << 3;        // A: 128 rows, all 512 thr
    const int t2 = tid & 255;
    const int brow = t2 >> 2, bkoff = (t2 & 3) << 3;          // B: 64 rows, 256 thr each
    const bool doB1 = tid < 256;

    {
        async_copy16(&sA[0][tid * 8], &A[(size_t)(m0 + arow) * K + akoff]);
        if (doB1) async_copy16(&sB1[0][t2 * 8], &B1[(size_t)(n0 + brow) * K + bkoff]);
        else      async_copy16(&sB3[0][t2 * 8], &B3[(size_t)(n0 + brow) * K + bkoff]);
    }
    for (int kt = 0; kt < 32; ++kt) {
        __syncthreads();
        const int cur = kt & 1, nxt = cur ^ 1;
        if (kt + 1 < 32) {
            const int kb = (kt + 1) << 5;
            async_copy16(&sA[nxt][tid * 8], &A[(size_t)(m0 + arow) * K + kb + akoff]);
            if (doB1) async_copy16(&sB1[nxt][t2 * 8], &B1[(size_t)(n0 + brow) * K + kb + bkoff]);
            else      async_copy16(&sB3[nxt][t2 * 8], &B3[(size_t)(n0 + brow) * K + kb + bkoff]);
        }
        bf16x8 af[4], bf1, bf3;
        #pragma unroll
        for (int i = 0; i < 4; ++i)
            af[i] = *(const bf16x8*)&sA[cur][(mwo + i * 16 + r16) * 32 + kreg];
        bf1 = *(const bf16x8*)&sB1[cur][(nwo + r16) * 32 + kreg];
        bf3 = *(const bf16x8*)&sB3[cur][(nwo + r16) * 32 + kreg];
        #pragma unroll
        for (int mi = 0; mi < 4; ++mi) {
            acc1[mi] = __builtin_amdgcn_mfma_f32_16x16x32_bf16(af[mi], bf1, acc1[mi], 0, 0, 0);
            acc3[mi] = __builtin_amdgcn_mfma_f32_16x16x32_bf16(af[mi], bf3, acc3[mi], 0, 0, 0);
        }
    }

    int col = n0 + nwo + r16;
    float bv1 = (col < 3280) ? b1[col] : 0.0f;
    float bv3 = (col < 3280) ? b3[col] : 0.0f;
    #pragma unroll
    for (int mi = 0; mi < 4; ++mi) {
        #pragma unroll
        for (int r = 0; r < 4; ++r) {
            int row = m0 + mwo + mi * 16 + quad * 4 + r;
            float z1 = acc1[mi][r] + bv1;
            float z3 = acc3[mi][r] + bv3;
            float s = z1 / (1.0f + __expf(-z1));
            G[(size_t)row * N + col] = (bf16)(s * z3);
        }
    }
}

extern "C" void kernel_launch(void* const* d_in, const int* in_sizes, int n_in,
                              void* d_out, int out_size, void* d_ws, size_t ws_size,
                              hipStream_t stream) {
    const float* x       = (const float*)d_in[0];
    const float* wq_w    = (const float*)d_in[1];
    const float* wq_b    = (const float*)d_in[2];
    const float* wk_w    = (const float*)d_in[3];
    const float* wk_b    = (const float*)d_in[4];
    const float* wv_w    = (const float*)d_in[5];
    const float* wv_b    = (const float*)d_in[6];
    const float* wo_w    = (const float*)d_in[7];
    const float* wo_b    = (const float*)d_in[8];
    const float* q_norm_w= (const float*)d_in[9];
    const float* k_norm_w= (const float*)d_in[10];
    const float* seq_norm_w      = (const float*)d_in[11];
    const float* seq_post_norm_w = (const float*)d_in[12];
    const float* ffn_norm_w      = (const float*)d_in[13];
    const float* ffn_post_norm_w = (const float*)d_in[14];
    const float* w1_w    = (const float*)d_in[15];
    const float* w1_b    = (const float*)d_in[16];
    const float* w2_w    = (const float*)d_in[17];
    const float* w2_b    = (const float*)d_in[18];
    const float* w3_w    = (const float*)d_in[19];
    const float* w3_b    = (const float*)d_in[20];
    const int*   winp    = (const int*)d_in[21];
    float* out = (float*)d_out;

    const size_t SZ_W   = 2097152;    // 1024*1024*2
    const size_t SZ_WP  = 6815744;    // 3328*1024*2
    const size_t SZ_ACT = 8388608;    // 4096*1024*2
    const size_t SZ_H   = 16777216;   // 4096*1024*4
    const size_t SZ_P   = 16777216;   // 4096*1024*4

    char* p = (char*)d_ws;
    bf16* Wq  = (bf16*)p; p += SZ_W;
    bf16* Wk  = (bf16*)p; p += SZ_W;
    bf16* Wv  = (bf16*)p; p += SZ_W;
    bf16* Wo  = (bf16*)p; p += SZ_W;
    bf16* W1p = (bf16*)p; p += SZ_WP;
    bf16* W3p = (bf16*)p; p += SZ_WP;
    bf16* W2p = (bf16*)p; p += SZ_WP;
    float* h  = (float*)p; p += SZ_H;
    bf16* hn  = (bf16*)p; p += SZ_ACT;
    float* part = (float*)p; p += SZ_P;
    char* regionA = p;  // aliased: attn-phase buffers, later g
    bf16* xn    = (bf16*)(regionA);
    bf16* qb    = (bf16*)(regionA + 1 * SZ_ACT);
    bf16* kb    = (bf16*)(regionA + 2 * SZ_ACT);
    bf16* vtb   = (bf16*)(regionA + 3 * SZ_ACT);
    bf16* attnb = (bf16*)(regionA + 4 * SZ_ACT);
    bf16* g     = (bf16*)(regionA);   // 27.3 MB; reuses xn..vtb after attention phase

    // 1) prep: all converts + rmsnorm(x)
    prep<<<dim3(15872), dim3(256), 0, stream>>>(wq_w, wk_w, wv_w, wo_w, Wq, Wk, Wv, Wo,
                                                w1_w, w3_w, W1p, W3p, w2_w, W2p,
                                                x, seq_norm_w, xn);

    // 2) QKV projections; q,k head-normed; v transposed
    gemm_qkv<<<dim3(32, 8, 3), dim3(256), 0, stream>>>(xn, Wq, Wk, Wv, wq_b, wk_b, wv_b,
                                                       q_norm_w, k_norm_w, qb, kb, vtb);

    // 3) windowed causal attention, 128 q-rows/block
    attn_win<<<dim3(8, 16, 4), dim3(512), 0, stream>>>(qb, kb, vtb, winp, attnb);

    // 4) O-projection -> f32 (K=1024)
    gemm_nk<<<dim3(64, 8), dim3(256), 0, stream>>>(attnb, Wo, part, 1024);

    // 5) h = x + rmsnorm(part+wo_b, seq_post); hn = rmsnorm(h, ffn_norm)
    resid_norm<true><<<dim3(512), dim3(512), 0, stream>>>(x, part, wo_b,
                                                          seq_post_norm_w, ffn_norm_w, h, hn);

    // 6) fused FFN1, 128x64 tiles (occupancy-tuned)
    gemm_ffn1<<<dim3(32, 52), dim3(512), 0, stream>>>(hn, W1p, W3p, w1_b, w3_b, g);

    // 7) FFN2 -> f32 (K=3328, 104 iters)
    gemm_nk<<<dim3(64, 8), dim3(256), 0, stream>>>(g, W2p, part, 3328);

    // 8) out = h + rmsnorm(part+w2_b, ffn_post)
    resid_norm<false><<<dim3(512), dim3(512), 0, stream>>>(h, part, w2_b,
                                                           ffn_post_norm_w, nullptr, out, nullptr);
}

// Round 9
// 375.654 us; speedup vs baseline: 1.0278x; 1.0278x over previous
//
#include <hip/hip_runtime.h>
#include <cmath>
#include <cstdint>

typedef __bf16 bf16;
typedef bf16 bf16x4 __attribute__((ext_vector_type(4)));
typedef bf16 bf16x8 __attribute__((ext_vector_type(8)));
typedef float f32x4 __attribute__((ext_vector_type(4)));
typedef unsigned int u32;
typedef u32 u32x4 __attribute__((ext_vector_type(4)));

#define EPS 1e-5f

__device__ __forceinline__ float clipf(float v) {
    return fminf(fmaxf(v, -10000.0f), 10000.0f);
}
__device__ __forceinline__ float fin0(float v) { return isfinite(v) ? v : 0.0f; }

__device__ __forceinline__ void async_copy16(void* lds, const void* g) {
    __builtin_amdgcn_global_load_lds((__attribute__((address_space(1))) void*)(void*)g,
                                     (__attribute__((address_space(3))) void*)lds,
                                     16, 0, 0);
}

// ================= prep: all weight converts + input rmsnorm, one dispatch =================
// flat grid 15872 blocks x 256 thr.
__global__ __launch_bounds__(256) void prep(const float* __restrict__ wq, const float* __restrict__ wk,
                                            const float* __restrict__ wv, const float* __restrict__ wo,
                                            bf16* __restrict__ Wq, bf16* __restrict__ Wk,
                                            bf16* __restrict__ Wv, bf16* __restrict__ Wo,
                                            const float* __restrict__ w1, const float* __restrict__ w3,
                                            bf16* __restrict__ W1p, bf16* __restrict__ W3p,
                                            const float* __restrict__ w2, bf16* __restrict__ W2p,
                                            const float* __restrict__ x, const float* __restrict__ snw,
                                            bf16* __restrict__ xn) {
    const int bid = blockIdx.x, t = threadIdx.x;
    if (bid < 4096) {
        int z = bid >> 10, r = bid & 1023;
        const float* in = (z == 0) ? wq : (z == 1) ? wk : (z == 2) ? wv : wo;
        bf16* out = (z == 0) ? Wq : (z == 1) ? Wk : (z == 2) ? Wv : Wo;
        f32x4 v = ((const f32x4*)(in + (size_t)r * 1024))[t];
        bf16x4 o = {(bf16)v[0], (bf16)v[1], (bf16)v[2], (bf16)v[3]};
        ((bf16x4*)(out + (size_t)r * 1024))[t] = o;
    } else if (bid < 10752) {
        int b2 = bid - 4096;
        int which = b2 >= 3328;
        int r = b2 - (which ? 3328 : 0);
        const float* in = which ? w3 : w1;
        bf16* out = which ? W3p : W1p;
        bf16x4 o = {(bf16)0.f, (bf16)0.f, (bf16)0.f, (bf16)0.f};
        if (r < 3280) {
            f32x4 v = ((const f32x4*)(in + (size_t)r * 1024))[t];
            o[0] = (bf16)v[0]; o[1] = (bf16)v[1]; o[2] = (bf16)v[2]; o[3] = (bf16)v[3];
        }
        ((bf16x4*)(out + (size_t)r * 1024))[t] = o;
    } else if (bid < 11776) {
        int r = bid - 10752;
        for (int c4 = t * 4; c4 < 3328; c4 += 1024) {
            bf16x4 o = {(bf16)0.f, (bf16)0.f, (bf16)0.f, (bf16)0.f};
            if (c4 + 3 < 3280) {
                f32x4 v = *(const f32x4*)(w2 + (size_t)r * 3280 + c4);
                o[0] = (bf16)v[0]; o[1] = (bf16)v[1]; o[2] = (bf16)v[2]; o[3] = (bf16)v[3];
            } else {
                #pragma unroll
                for (int j = 0; j < 4; ++j)
                    if (c4 + j < 3280) o[j] = (bf16)w2[(size_t)r * 3280 + c4 + j];
            }
            *(bf16x4*)(W2p + (size_t)r * 3328 + c4) = o;
        }
    } else {
        __shared__ float sred[4];
        int row = bid - 11776;
        f32x4 xv = ((const f32x4*)(x + (size_t)row * 1024))[t];
        f32x4 cv;
        cv[0] = clipf(xv[0]); cv[1] = clipf(xv[1]); cv[2] = clipf(xv[2]); cv[3] = clipf(xv[3]);
        float ss = cv[0]*cv[0] + cv[1]*cv[1] + cv[2]*cv[2] + cv[3]*cv[3];
        #pragma unroll
        for (int off = 32; off >= 1; off >>= 1) ss += __shfl_xor(ss, off, 64);
        if ((t & 63) == 0) sred[t >> 6] = ss;
        __syncthreads();
        float tot = sred[0] + sred[1] + sred[2] + sred[3];
        float rms = sqrtf(fmaxf(tot * (1.0f / 1024.0f), EPS) + EPS);
        f32x4 wv_ = ((const f32x4*)snw)[t];
        bf16x4 o;
        o[0] = (bf16)fin0(cv[0] / rms * wv_[0]);
        o[1] = (bf16)fin0(cv[1] / rms * wv_[1]);
        o[2] = (bf16)fin0(cv[2] / rms * wv_[2]);
        o[3] = (bf16)fin0(cv[3] / rms * wv_[3]);
        *(bf16x4*)(xn + (size_t)row * 1024 + t * 4) = o;
    }
}

// ================= QKV GEMM (dbuf), fused head-rmsnorm (q,k), vT epilogue =================
// grid (32, 8, 3), block 256.
__global__ __launch_bounds__(256) void gemm_qkv(const bf16* __restrict__ A,
                                                const bf16* __restrict__ B0,
                                                const bf16* __restrict__ B1,
                                                const bf16* __restrict__ B2,
                                                const float* __restrict__ g0,
                                                const float* __restrict__ g1,
                                                const float* __restrict__ g2,
                                                const float* __restrict__ qnw,
                                                const float* __restrict__ knw,
                                                bf16* __restrict__ C0,
                                                bf16* __restrict__ C1,
                                                bf16* __restrict__ VT) {
    const int z = blockIdx.z;
    const bf16* B = (z == 0) ? B0 : (z == 1) ? B1 : B2;
    const float* bias = (z == 0) ? g0 : (z == 1) ? g1 : g2;
    const float* hw = (z == 0) ? qnw : knw;

    __shared__ __align__(16) bf16 sA[2][128 * 32];
    __shared__ __align__(16) bf16 sB[2][128 * 32];
    const int tid = threadIdx.x;
    const int w = tid >> 6, lane = tid & 63;
    const int m0 = blockIdx.x * 128;
    const int n0 = blockIdx.y * 128;
    const int mwo = (w >> 1) * 64, nwo = (w & 1) * 64;
    const int r16 = lane & 15, quad = lane >> 4;
    const int kreg = quad * 8;
    const int K = 1024, N = 1024;

    f32x4 zero = {0.f, 0.f, 0.f, 0.f};
    f32x4 acc[4][4];
    #pragma unroll
    for (int i = 0; i < 4; ++i)
        #pragma unroll
        for (int j = 0; j < 4; ++j) acc[i][j] = zero;

    const int c0 = tid, c1 = tid + 256;
    const int am0 = c0 >> 2, ak0 = (c0 & 3) << 3;
    const int am1 = c1 >> 2, ak1 = (c1 & 3) << 3;

    {
        async_copy16(&sA[0][c0 * 8], &A[(size_t)(m0 + am0) * K + ak0]);
        async_copy16(&sA[0][c1 * 8], &A[(size_t)(m0 + am1) * K + ak1]);
        async_copy16(&sB[0][c0 * 8], &B[(size_t)(n0 + am0) * K + ak0]);
        async_copy16(&sB[0][c1 * 8], &B[(size_t)(n0 + am1) * K + ak1]);
    }
    for (int kt = 0; kt < 32; ++kt) {
        __syncthreads();
        const int cur = kt & 1, nxt = cur ^ 1;
        if (kt + 1 < 32) {
            const int kb = (kt + 1) << 5;
            async_copy16(&sA[nxt][c0 * 8], &A[(size_t)(m0 + am0) * K + kb + ak0]);
            async_copy16(&sA[nxt][c1 * 8], &A[(size_t)(m0 + am1) * K + kb + ak1]);
            async_copy16(&sB[nxt][c0 * 8], &B[(size_t)(n0 + am0) * K + kb + ak0]);
            async_copy16(&sB[nxt][c1 * 8], &B[(size_t)(n0 + am1) * K + kb + ak1]);
        }
        bf16x8 af[4], bfr[4];
        #pragma unroll
        for (int i = 0; i < 4; ++i) {
            af[i]  = *(const bf16x8*)&sA[cur][(mwo + i * 16 + r16) * 32 + kreg];
            bfr[i] = *(const bf16x8*)&sB[cur][(nwo + i * 16 + r16) * 32 + kreg];
        }
        #pragma unroll
        for (int mi = 0; mi < 4; ++mi)
            #pragma unroll
            for (int ni = 0; ni < 4; ++ni)
                acc[mi][ni] = __builtin_amdgcn_mfma_f32_16x16x32_bf16(af[mi], bfr[ni], acc[mi][ni], 0, 0, 0);
    }

    float bv[4];
    #pragma unroll
    for (int ni = 0; ni < 4; ++ni) bv[ni] = bias[n0 + nwo + ni * 16 + r16];

    if (z < 2) {
        bf16* C = (z == 0) ? C0 : C1;
        float nwv[4];
        #pragma unroll
        for (int ni = 0; ni < 4; ++ni) nwv[ni] = hw[ni * 16 + r16];
        #pragma unroll
        for (int mi = 0; mi < 4; ++mi) {
            #pragma unroll
            for (int r = 0; r < 4; ++r) {
                float v[4], ss = 0.0f;
                #pragma unroll
                for (int ni = 0; ni < 4; ++ni) {
                    v[ni] = clipf(acc[mi][ni][r] + bv[ni]);
                    ss += v[ni] * v[ni];
                }
                ss += __shfl_xor(ss, 1, 64);
                ss += __shfl_xor(ss, 2, 64);
                ss += __shfl_xor(ss, 4, 64);
                ss += __shfl_xor(ss, 8, 64);
                float rms = sqrtf(fmaxf(ss * (1.0f / 64.0f), EPS) + EPS);
                int row = m0 + mwo + mi * 16 + quad * 4 + r;
                #pragma unroll
                for (int ni = 0; ni < 4; ++ni) {
                    int col = n0 + nwo + ni * 16 + r16;
                    C[(size_t)row * N + col] = (bf16)fin0(v[ni] / rms * nwv[ni]);
                }
            }
        }
    } else {
        const int b_ = m0 >> 10;
        const int tokbase = (m0 & 1023) + mwo;
        #pragma unroll
        for (int ni = 0; ni < 4; ++ni) {
            int col = n0 + nwo + ni * 16 + r16;
            int h_ = col >> 6, hd = col & 63;
            bf16* dst = VT + (((size_t)b_ * 16 + h_) * 64 + hd) * 1024;
            #pragma unroll
            for (int mi = 0; mi < 4; ++mi) {
                bf16x4 pack;
                #pragma unroll
                for (int r = 0; r < 4; ++r) pack[r] = (bf16)(acc[mi][ni][r] + bv[ni]);
                *(bf16x4*)&dst[tokbase + mi * 16 + quad * 4] = pack;
            }
        }
    }
}

// ================= windowed causal flash attention, FIXED-MAX softmax =================
// grid: (L/64, H, B), block 256. q/k: (B,L,H,64); vt: (B,H,64,L).
// Q,K are per-head rmsnorm'd => ||q||=||k||=8 => |score*scale| <= 8 (Cauchy-Schwarz).
// Softmax is shift-invariant: use constant max 8.0 -> no running max, no alpha rescale,
// row-sum kept as per-lane partial, reduced ONCE at the end.
__global__ __launch_bounds__(256) void attn_win(const bf16* __restrict__ q,
                                                const bf16* __restrict__ k,
                                                const bf16* __restrict__ vt,
                                                const int* __restrict__ winp,
                                                bf16* __restrict__ o) {
    __shared__ __align__(16) bf16 sQ[64 * 64];
    __shared__ __align__(16) bf16 sK[64 * 64];
    __shared__ __align__(16) bf16 sVt[64 * 80];
    __shared__ __align__(16) bf16 sP[64 * 64];
    const int tid = threadIdx.x, w = tid >> 6, lane = tid & 63;
    const int qt = blockIdx.x, h = blockIdx.y, b = blockIdx.z;
    const int q0 = qt * 64;
    const int win = *winp;
    const float scale = 0.125f;
    const int r16 = lane & 15, quad = lane >> 4;

    {
        int qr0 = tid >> 3, col0 = (tid & 7) * 8;
        async_copy16(&sQ[tid * 8], &q[(((size_t)b * 1024 + q0 + qr0) * 16 + h) * 64 + col0]);
        int c1 = tid + 256;
        int qr1 = c1 >> 3, col1 = (c1 & 7) * 8;
        async_copy16(&sQ[c1 * 8], &q[(((size_t)b * 1024 + q0 + qr1) * 16 + h) * 64 + col1]);
    }
    __syncthreads();
    bf16x8 aq0 = *(const bf16x8*)&sQ[(w * 16 + r16) * 64 + quad * 8];
    bf16x8 aq1 = *(const bf16x8*)&sQ[(w * 16 + r16) * 64 + 32 + quad * 8];

    float Lr[4];                       // per-lane partial row sums (16 lanes/row)
    f32x4 zero = {0.f, 0.f, 0.f, 0.f};
    f32x4 accO[4];
    #pragma unroll
    for (int r = 0; r < 4; ++r) Lr[r] = 0.0f;
    #pragma unroll
    for (int nf = 0; nf < 4; ++nf) accO[nf] = zero;

    int lo = q0 - (win - 1); if (lo < 0) lo = 0;
    const int kt0 = lo >> 6;
    const bf16* vth = vt + ((size_t)b * 16 + h) * 64 * 1024;

    for (int kt = kt0; kt <= qt; ++kt) {
        __syncthreads();
        {
            int col0 = (tid & 7) * 8;
            async_copy16(&sK[tid * 8], &k[(((size_t)b * 1024 + kt * 64 + (tid >> 3)) * 16 + h) * 64 + col0]);
            int c1 = tid + 256;
            int col1 = (c1 & 7) * 8;
            async_copy16(&sK[c1 * 8], &k[(((size_t)b * 1024 + kt * 64 + (c1 >> 3)) * 16 + h) * 64 + col1]);
        }
        #pragma unroll
        for (int c = tid; c < 512; c += 256) {
            int hd = c >> 3, koff = (c & 7) * 8;
            *(u32x4*)&sVt[hd * 80 + koff] = *(const u32x4*)&vth[(size_t)hd * 1024 + kt * 64 + koff];
        }
        __syncthreads();

        f32x4 sf[4];
        #pragma unroll
        for (int nf = 0; nf < 4; ++nf) {
            bf16x8 bk0 = *(const bf16x8*)&sK[(nf * 16 + r16) * 64 + quad * 8];
            bf16x8 bk1 = *(const bf16x8*)&sK[(nf * 16 + r16) * 64 + 32 + quad * 8];
            f32x4 accS = zero;
            accS = __builtin_amdgcn_mfma_f32_16x16x32_bf16(aq0, bk0, accS, 0, 0, 0);
            accS = __builtin_amdgcn_mfma_f32_16x16x32_bf16(aq1, bk1, accS, 0, 0, 0);
            sf[nf] = accS;
        }

        #pragma unroll
        for (int r = 0; r < 4; ++r) {
            int i = q0 + w * 16 + quad * 4 + r;
            float ps = 0.0f;
            #pragma unroll
            for (int nf = 0; nf < 4; ++nf) {
                int j = kt * 64 + nf * 16 + r16;
                bool ok = (j <= i) && (i - j < win);
                float pv = ok ? __expf(sf[nf][r] * scale - 8.0f) : 0.0f;
                ps += pv;
                sP[(w * 16 + quad * 4 + r) * 64 + nf * 16 + r16] = (bf16)pv;
            }
            Lr[r] += ps;
        }
        __syncthreads();

        bf16x8 ap0 = *(const bf16x8*)&sP[(w * 16 + r16) * 64 + quad * 8];
        bf16x8 ap1 = *(const bf16x8*)&sP[(w * 16 + r16) * 64 + 32 + quad * 8];
        #pragma unroll
        for (int nf = 0; nf < 4; ++nf) {
            bf16x8 bv0 = *(const bf16x8*)&sVt[(nf * 16 + r16) * 80 + quad * 8];
            bf16x8 bv1 = *(const bf16x8*)&sVt[(nf * 16 + r16) * 80 + 32 + quad * 8];
            accO[nf] = __builtin_amdgcn_mfma_f32_16x16x32_bf16(ap0, bv0, accO[nf], 0, 0, 0);
            accO[nf] = __builtin_amdgcn_mfma_f32_16x16x32_bf16(ap1, bv1, accO[nf], 0, 0, 0);
        }
    }

    #pragma unroll
    for (int r = 0; r < 4; ++r) {
        float l = Lr[r];
        l += __shfl_xor(l, 1, 64);
        l += __shfl_xor(l, 2, 64);
        l += __shfl_xor(l, 4, 64);
        l += __shfl_xor(l, 8, 64);
        float inv = (l > 0.0f) ? 1.0f / l : 0.0f;
        int row = q0 + w * 16 + quad * 4 + r;
        #pragma unroll
        for (int nf = 0; nf < 4; ++nf) {
            float ov = fin0(accO[nf][r] * inv);
            o[(((size_t)b * 1024 + row) * 16 + h) * 64 + nf * 16 + r16] = (bf16)ov;
        }
    }
}

// ================= non-split 64x128-tile GEMM -> f32 (no bias) =================
// C[M,1024] = A[M,K] @ B[1024,K]^T. grid (M/64, 8), block 256 (4 waves, 32x64/wave).
__global__ __launch_bounds__(256) void gemm_nk(const bf16* __restrict__ A,
                                               const bf16* __restrict__ B,
                                               float* __restrict__ C, int K) {
    __shared__ __align__(16) bf16 sA[2][64 * 32];
    __shared__ __align__(16) bf16 sB[2][128 * 32];
    const int tid = threadIdx.x;
    const int w = tid >> 6, lane = tid & 63;
    const int m0 = blockIdx.x * 64, n0 = blockIdx.y * 128;
    const int mwo = (w >> 1) * 32, nwo = (w & 1) * 64;
    const int r16 = lane & 15, quad = lane >> 4, kreg = quad * 8;
    const int N = 1024;

    const int arow = tid >> 2, akoff = (tid & 3) << 3;
    const int c1 = tid + 256;
    const int brow1 = c1 >> 2, bkoff1 = (c1 & 3) << 3;

    f32x4 zero = {0.f, 0.f, 0.f, 0.f};
    f32x4 acc[2][4];
    #pragma unroll
    for (int i = 0; i < 2; ++i)
        #pragma unroll
        for (int j = 0; j < 4; ++j) acc[i][j] = zero;

    {
        async_copy16(&sA[0][tid * 8], &A[(size_t)(m0 + arow) * K + akoff]);
        async_copy16(&sB[0][tid * 8], &B[(size_t)(n0 + arow) * K + akoff]);
        async_copy16(&sB[0][c1 * 8], &B[(size_t)(n0 + brow1) * K + bkoff1]);
    }
    const int kIters = K >> 5;
    for (int kt = 0; kt < kIters; ++kt) {
        __syncthreads();
        const int cur = kt & 1, nxt = cur ^ 1;
        if (kt + 1 < kIters) {
            const int kb = (kt + 1) << 5;
            async_copy16(&sA[nxt][tid * 8], &A[(size_t)(m0 + arow) * K + kb + akoff]);
            async_copy16(&sB[nxt][tid * 8], &B[(size_t)(n0 + arow) * K + kb + akoff]);
            async_copy16(&sB[nxt][c1 * 8], &B[(size_t)(n0 + brow1) * K + kb + bkoff1]);
        }
        bf16x8 af[2], bfr[4];
        #pragma unroll
        for (int i = 0; i < 2; ++i)
            af[i] = *(const bf16x8*)&sA[cur][(mwo + i * 16 + r16) * 32 + kreg];
        #pragma unroll
        for (int i = 0; i < 4; ++i)
            bfr[i] = *(const bf16x8*)&sB[cur][(nwo + i * 16 + r16) * 32 + kreg];
        #pragma unroll
        for (int mi = 0; mi < 2; ++mi)
            #pragma unroll
            for (int ni = 0; ni < 4; ++ni)
                acc[mi][ni] = __builtin_amdgcn_mfma_f32_16x16x32_bf16(af[mi], bfr[ni], acc[mi][ni], 0, 0, 0);
    }

    #pragma unroll
    for (int mi = 0; mi < 2; ++mi)
        #pragma unroll
        for (int ni = 0; ni < 4; ++ni) {
            int col = n0 + nwo + ni * 16 + r16;
            #pragma unroll
            for (int r = 0; r < 4; ++r) {
                int row = m0 + mwo + mi * 16 + quad * 4 + r;
                C[(size_t)row * N + col] = acc[mi][ni][r];
            }
        }
}

// ================= resid+norm: a = p0+bias; h = x + rmsnorm(a, wpost); opt hn = rmsnorm(h, wnext) ====
template <bool EMIT>
__global__ __launch_bounds__(512) void resid_norm(const float* __restrict__ xres,
                                                  const float* __restrict__ p0,
                                                  const float* __restrict__ bias,
                                                  const float* __restrict__ wpost,
                                                  const float* __restrict__ wnext,
                                                  float* __restrict__ hout,
                                                  bf16* __restrict__ hnout) {
    __shared__ float sred[8];
    const int tid = threadIdx.x;
    const int grp = tid >> 8, t = tid & 255;
    const int w4 = (tid >> 6) & 3;
    for (int it = 0; it < 4; ++it) {
        int row = it * 1024 + blockIdx.x * 2 + grp;
        f32x4 a0 = ((const f32x4*)(p0 + (size_t)row * 1024))[t];
        f32x4 bv = ((const f32x4*)bias)[t];
        f32x4 af;
        af[0] = clipf(a0[0] + bv[0]);
        af[1] = clipf(a0[1] + bv[1]);
        af[2] = clipf(a0[2] + bv[2]);
        af[3] = clipf(a0[3] + bv[3]);
        float ss = af[0]*af[0] + af[1]*af[1] + af[2]*af[2] + af[3]*af[3];
        #pragma unroll
        for (int off = 32; off >= 1; off >>= 1) ss += __shfl_xor(ss, off, 64);
        __syncthreads();
        if ((tid & 63) == 0) sred[grp * 4 + w4] = ss;
        __syncthreads();
        float tot = sred[grp*4+0] + sred[grp*4+1] + sred[grp*4+2] + sred[grp*4+3];
        float rms1 = sqrtf(fmaxf(tot * (1.0f / 1024.0f), EPS) + EPS);
        f32x4 xv = ((const f32x4*)(xres + (size_t)row * 1024))[t];
        f32x4 wp = ((const f32x4*)wpost)[t];
        f32x4 hv;
        hv[0] = xv[0] + fin0(af[0] / rms1 * wp[0]);
        hv[1] = xv[1] + fin0(af[1] / rms1 * wp[1]);
        hv[2] = xv[2] + fin0(af[2] / rms1 * wp[2]);
        hv[3] = xv[3] + fin0(af[3] / rms1 * wp[3]);
        ((f32x4*)(hout + (size_t)row * 1024))[t] = hv;
        if (EMIT) {
            f32x4 cv;
            cv[0] = clipf(hv[0]); cv[1] = clipf(hv[1]); cv[2] = clipf(hv[2]); cv[3] = clipf(hv[3]);
            float ss2 = cv[0]*cv[0] + cv[1]*cv[1] + cv[2]*cv[2] + cv[3]*cv[3];
            #pragma unroll
            for (int off = 32; off >= 1; off >>= 1) ss2 += __shfl_xor(ss2, off, 64);
            __syncthreads();
            if ((tid & 63) == 0) sred[grp * 4 + w4] = ss2;
            __syncthreads();
            float tot2 = sred[grp*4+0] + sred[grp*4+1] + sred[grp*4+2] + sred[grp*4+3];
            float rms2 = sqrtf(fmaxf(tot2 * (1.0f / 1024.0f), EPS) + EPS);
            f32x4 wn = ((const f32x4*)wnext)[t];
            bf16x4 o;
            o[0] = (bf16)fin0(cv[0] / rms2 * wn[0]);
            o[1] = (bf16)fin0(cv[1] / rms2 * wn[1]);
            o[2] = (bf16)fin0(cv[2] / rms2 * wn[2]);
            o[3] = (bf16)fin0(cv[3] / rms2 * wn[3]);
            *(bf16x4*)(hnout + (size_t)row * 1024 + t * 4) = o;
        }
    }
}

// ================= fused FFN1 (r7-best, 128x128, dbuf): g = silu(A@W1^T+b1)*(A@W3^T+b3) =======
// grid (32, 26), block 512 (8 waves, 64x32 per stream per wave).
__global__ __launch_bounds__(512) void gemm_ffn1(const bf16* __restrict__ A,
                                                 const bf16* __restrict__ B1,
                                                 const bf16* __restrict__ B3,
                                                 const float* __restrict__ b1,
                                                 const float* __restrict__ b3,
                                                 bf16* __restrict__ G) {
    __shared__ __align__(16) bf16 sA[2][128 * 32];
    __shared__ __align__(16) bf16 sB1[2][128 * 32];
    __shared__ __align__(16) bf16 sB3[2][128 * 32];
    const int tid = threadIdx.x;
    const int w = tid >> 6, lane = tid & 63;
    const int m0 = blockIdx.x * 128;
    const int n0 = blockIdx.y * 128;
    const int mwo = (w >> 2) * 64, nwo = (w & 3) * 32;
    const int r16 = lane & 15, quad = lane >> 4;
    const int kreg = quad * 8;
    const int K = 1024, N = 3328;

    f32x4 zero = {0.f, 0.f, 0.f, 0.f};
    f32x4 acc1[4][2], acc3[4][2];
    #pragma unroll
    for (int i = 0; i < 4; ++i)
        #pragma unroll
        for (int j = 0; j < 2; ++j) { acc1[i][j] = zero; acc3[i][j] = zero; }

    const int arow = tid >> 2, akoff = (tid & 3) << 3;

    {
        async_copy16(&sA[0][tid * 8],  &A[(size_t)(m0 + arow) * K + akoff]);
        async_copy16(&sB1[0][tid * 8], &B1[(size_t)(n0 + arow) * K + akoff]);
        async_copy16(&sB3[0][tid * 8], &B3[(size_t)(n0 + arow) * K + akoff]);
    }
    for (int kt = 0; kt < 32; ++kt) {
        __syncthreads();
        const int cur = kt & 1, nxt = cur ^ 1;
        if (kt + 1 < 32) {
            const int kb = (kt + 1) << 5;
            async_copy16(&sA[nxt][tid * 8],  &A[(size_t)(m0 + arow) * K + kb + akoff]);
            async_copy16(&sB1[nxt][tid * 8], &B1[(size_t)(n0 + arow) * K + kb + akoff]);
            async_copy16(&sB3[nxt][tid * 8], &B3[(size_t)(n0 + arow) * K + kb + akoff]);
        }
        bf16x8 af[4], bf1[2], bf3[2];
        #pragma unroll
        for (int i = 0; i < 4; ++i)
            af[i]  = *(const bf16x8*)&sA[cur][(mwo + i * 16 + r16) * 32 + kreg];
        #pragma unroll
        for (int i = 0; i < 2; ++i) {
            bf1[i] = *(const bf16x8*)&sB1[cur][(nwo + i * 16 + r16) * 32 + kreg];
            bf3[i] = *(const bf16x8*)&sB3[cur][(nwo + i * 16 + r16) * 32 + kreg];
        }
        #pragma unroll
        for (int mi = 0; mi < 4; ++mi)
            #pragma unroll
            for (int ni = 0; ni < 2; ++ni) {
                acc1[mi][ni] = __builtin_amdgcn_mfma_f32_16x16x32_bf16(af[mi], bf1[ni], acc1[mi][ni], 0, 0, 0);
                acc3[mi][ni] = __builtin_amdgcn_mfma_f32_16x16x32_bf16(af[mi], bf3[ni], acc3[mi][ni], 0, 0, 0);
            }
    }

    #pragma unroll
    for (int ni = 0; ni < 2; ++ni) {
        int col = n0 + nwo + ni * 16 + r16;
        float bv1 = (col < 3280) ? b1[col] : 0.0f;
        float bv3 = (col < 3280) ? b3[col] : 0.0f;
        #pragma unroll
        for (int mi = 0; mi < 4; ++mi) {
            #pragma unroll
            for (int r = 0; r < 4; ++r) {
                int row = m0 + mwo + mi * 16 + quad * 4 + r;
                float z1 = acc1[mi][ni][r] + bv1;
                float z3 = acc3[mi][ni][r] + bv3;
                float s = z1 / (1.0f + __expf(-z1));
                G[(size_t)row * N + col] = (bf16)(s * z3);
            }
        }
    }
}

extern "C" void kernel_launch(void* const* d_in, const int* in_sizes, int n_in,
                              void* d_out, int out_size, void* d_ws, size_t ws_size,
                              hipStream_t stream) {
    const float* x       = (const float*)d_in[0];
    const float* wq_w    = (const float*)d_in[1];
    const float* wq_b    = (const float*)d_in[2];
    const float* wk_w    = (const float*)d_in[3];
    const float* wk_b    = (const float*)d_in[4];
    const float* wv_w    = (const float*)d_in[5];
    const float* wv_b    = (const float*)d_in[6];
    const float* wo_w    = (const float*)d_in[7];
    const float* wo_b    = (const float*)d_in[8];
    const float* q_norm_w= (const float*)d_in[9];
    const float* k_norm_w= (const float*)d_in[10];
    const float* seq_norm_w      = (const float*)d_in[11];
    const float* seq_post_norm_w = (const float*)d_in[12];
    const float* ffn_norm_w      = (const float*)d_in[13];
    const float* ffn_post_norm_w = (const float*)d_in[14];
    const float* w1_w    = (const float*)d_in[15];
    const float* w1_b    = (const float*)d_in[16];
    const float* w2_w    = (const float*)d_in[17];
    const float* w2_b    = (const float*)d_in[18];
    const float* w3_w    = (const float*)d_in[19];
    const float* w3_b    = (const float*)d_in[20];
    const int*   winp    = (const int*)d_in[21];
    float* out = (float*)d_out;

    const size_t SZ_W   = 2097152;    // 1024*1024*2
    const size_t SZ_WP  = 6815744;    // 3328*1024*2
    const size_t SZ_ACT = 8388608;    // 4096*1024*2
    const size_t SZ_H   = 16777216;   // 4096*1024*4
    const size_t SZ_P   = 16777216;   // 4096*1024*4

    char* p = (char*)d_ws;
    bf16* Wq  = (bf16*)p; p += SZ_W;
    bf16* Wk  = (bf16*)p; p += SZ_W;
    bf16* Wv  = (bf16*)p; p += SZ_W;
    bf16* Wo  = (bf16*)p; p += SZ_W;
    bf16* W1p = (bf16*)p; p += SZ_WP;
    bf16* W3p = (bf16*)p; p += SZ_WP;
    bf16* W2p = (bf16*)p; p += SZ_WP;
    float* h  = (float*)p; p += SZ_H;
    bf16* hn  = (bf16*)p; p += SZ_ACT;
    float* part = (float*)p; p += SZ_P;
    char* regionA = p;  // aliased: attn-phase buffers, later g
    bf16* xn    = (bf16*)(regionA);
    bf16* qb    = (bf16*)(regionA + 1 * SZ_ACT);
    bf16* kb    = (bf16*)(regionA + 2 * SZ_ACT);
    bf16* vtb   = (bf16*)(regionA + 3 * SZ_ACT);
    bf16* attnb = (bf16*)(regionA + 4 * SZ_ACT);
    bf16* g     = (bf16*)(regionA);   // 27.3 MB; reuses xn..vtb after attention phase

    // 1) prep: all converts + rmsnorm(x)
    prep<<<dim3(15872), dim3(256), 0, stream>>>(wq_w, wk_w, wv_w, wo_w, Wq, Wk, Wv, Wo,
                                                w1_w, w3_w, W1p, W3p, w2_w, W2p,
                                                x, seq_norm_w, xn);

    // 2) QKV projections; q,k head-normed; v transposed
    gemm_qkv<<<dim3(32, 8, 3), dim3(256), 0, stream>>>(xn, Wq, Wk, Wv, wq_b, wk_b, wv_b,
                                                       q_norm_w, k_norm_w, qb, kb, vtb);

    // 3) windowed causal attention (fixed-max softmax)
    attn_win<<<dim3(16, 16, 4), dim3(256), 0, stream>>>(qb, kb, vtb, winp, attnb);

    // 4) O-projection -> f32 (K=1024)
    gemm_nk<<<dim3(64, 8), dim3(256), 0, stream>>>(attnb, Wo, part, 1024);

    // 5) h = x + rmsnorm(part+wo_b, seq_post); hn = rmsnorm(h, ffn_norm)
    resid_norm<true><<<dim3(512), dim3(512), 0, stream>>>(x, part, wo_b,
                                                          seq_post_norm_w, ffn_norm_w, h, hn);

    // 6) fused FFN1, 128x128 tiles (r7-best)
    gemm_ffn1<<<dim3(32, 26), dim3(512), 0, stream>>>(hn, W1p, W3p, w1_b, w3_b, g);

    // 7) FFN2 -> f32 (K=3328, 104 iters)
    gemm_nk<<<dim3(64, 8), dim3(256), 0, stream>>>(g, W2p, part, 3328);

    // 8) out = h + rmsnorm(part+w2_b, ffn_post)
    resid_norm<false><<<dim3(512), dim3(512), 0, stream>>>(h, part, w2_b,
                                                           ffn_post_norm_w, nullptr, out, nullptr);
}

// Round 10
// 368.300 us; speedup vs baseline: 1.0483x; 1.0200x over previous
//
#include <hip/hip_runtime.h>
#include <cmath>
#include <cstdint>

typedef __bf16 bf16;
typedef bf16 bf16x4 __attribute__((ext_vector_type(4)));
typedef bf16 bf16x8 __attribute__((ext_vector_type(8)));
typedef float f32x4 __attribute__((ext_vector_type(4)));
typedef unsigned int u32;
typedef u32 u32x4 __attribute__((ext_vector_type(4)));

#define EPS 1e-5f

__device__ __forceinline__ float clipf(float v) {
    return fminf(fmaxf(v, -10000.0f), 10000.0f);
}
__device__ __forceinline__ float fin0(float v) { return isfinite(v) ? v : 0.0f; }

__device__ __forceinline__ void async_copy16(void* lds, const void* g) {
    __builtin_amdgcn_global_load_lds((__attribute__((address_space(1))) void*)(void*)g,
                                     (__attribute__((address_space(3))) void*)lds,
                                     16, 0, 0);
}

// ================= prep: all weight converts + input rmsnorm, one dispatch =================
// flat grid 15872 blocks x 256 thr.
__global__ __launch_bounds__(256) void prep(const float* __restrict__ wq, const float* __restrict__ wk,
                                            const float* __restrict__ wv, const float* __restrict__ wo,
                                            bf16* __restrict__ Wq, bf16* __restrict__ Wk,
                                            bf16* __restrict__ Wv, bf16* __restrict__ Wo,
                                            const float* __restrict__ w1, const float* __restrict__ w3,
                                            bf16* __restrict__ W1p, bf16* __restrict__ W3p,
                                            const float* __restrict__ w2, bf16* __restrict__ W2p,
                                            const float* __restrict__ x, const float* __restrict__ snw,
                                            bf16* __restrict__ xn) {
    const int bid = blockIdx.x, t = threadIdx.x;
    if (bid < 4096) {
        int z = bid >> 10, r = bid & 1023;
        const float* in = (z == 0) ? wq : (z == 1) ? wk : (z == 2) ? wv : wo;
        bf16* out = (z == 0) ? Wq : (z == 1) ? Wk : (z == 2) ? Wv : Wo;
        f32x4 v = ((const f32x4*)(in + (size_t)r * 1024))[t];
        bf16x4 o = {(bf16)v[0], (bf16)v[1], (bf16)v[2], (bf16)v[3]};
        ((bf16x4*)(out + (size_t)r * 1024))[t] = o;
    } else if (bid < 10752) {
        int b2 = bid - 4096;
        int which = b2 >= 3328;
        int r = b2 - (which ? 3328 : 0);
        const float* in = which ? w3 : w1;
        bf16* out = which ? W3p : W1p;
        bf16x4 o = {(bf16)0.f, (bf16)0.f, (bf16)0.f, (bf16)0.f};
        if (r < 3280) {
            f32x4 v = ((const f32x4*)(in + (size_t)r * 1024))[t];
            o[0] = (bf16)v[0]; o[1] = (bf16)v[1]; o[2] = (bf16)v[2]; o[3] = (bf16)v[3];
        }
        ((bf16x4*)(out + (size_t)r * 1024))[t] = o;
    } else if (bid < 11776) {
        int r = bid - 10752;
        for (int c4 = t * 4; c4 < 3328; c4 += 1024) {
            bf16x4 o = {(bf16)0.f, (bf16)0.f, (bf16)0.f, (bf16)0.f};
            if (c4 + 3 < 3280) {
                f32x4 v = *(const f32x4*)(w2 + (size_t)r * 3280 + c4);
                o[0] = (bf16)v[0]; o[1] = (bf16)v[1]; o[2] = (bf16)v[2]; o[3] = (bf16)v[3];
            } else {
                #pragma unroll
                for (int j = 0; j < 4; ++j)
                    if (c4 + j < 3280) o[j] = (bf16)w2[(size_t)r * 3280 + c4 + j];
            }
            *(bf16x4*)(W2p + (size_t)r * 3328 + c4) = o;
        }
    } else {
        __shared__ float sred[4];
        int row = bid - 11776;
        f32x4 xv = ((const f32x4*)(x + (size_t)row * 1024))[t];
        f32x4 cv;
        cv[0] = clipf(xv[0]); cv[1] = clipf(xv[1]); cv[2] = clipf(xv[2]); cv[3] = clipf(xv[3]);
        float ss = cv[0]*cv[0] + cv[1]*cv[1] + cv[2]*cv[2] + cv[3]*cv[3];
        #pragma unroll
        for (int off = 32; off >= 1; off >>= 1) ss += __shfl_xor(ss, off, 64);
        if ((t & 63) == 0) sred[t >> 6] = ss;
        __syncthreads();
        float tot = sred[0] + sred[1] + sred[2] + sred[3];
        float rms = sqrtf(fmaxf(tot * (1.0f / 1024.0f), EPS) + EPS);
        f32x4 wv_ = ((const f32x4*)snw)[t];
        bf16x4 o;
        o[0] = (bf16)fin0(cv[0] / rms * wv_[0]);
        o[1] = (bf16)fin0(cv[1] / rms * wv_[1]);
        o[2] = (bf16)fin0(cv[2] / rms * wv_[2]);
        o[3] = (bf16)fin0(cv[3] / rms * wv_[3]);
        *(bf16x4*)(xn + (size_t)row * 1024 + t * 4) = o;
    }
}

// ================= QKV GEMM (dbuf), fused head-rmsnorm (q,k), vT epilogue =================
// grid (32, 8, 3), block 256.
__global__ __launch_bounds__(256) void gemm_qkv(const bf16* __restrict__ A,
                                                const bf16* __restrict__ B0,
                                                const bf16* __restrict__ B1,
                                                const bf16* __restrict__ B2,
                                                const float* __restrict__ g0,
                                                const float* __restrict__ g1,
                                                const float* __restrict__ g2,
                                                const float* __restrict__ qnw,
                                                const float* __restrict__ knw,
                                                bf16* __restrict__ C0,
                                                bf16* __restrict__ C1,
                                                bf16* __restrict__ VT) {
    const int z = blockIdx.z;
    const bf16* B = (z == 0) ? B0 : (z == 1) ? B1 : B2;
    const float* bias = (z == 0) ? g0 : (z == 1) ? g1 : g2;
    const float* hw = (z == 0) ? qnw : knw;

    __shared__ __align__(16) bf16 sA[2][128 * 32];
    __shared__ __align__(16) bf16 sB[2][128 * 32];
    const int tid = threadIdx.x;
    const int w = tid >> 6, lane = tid & 63;
    const int m0 = blockIdx.x * 128;
    const int n0 = blockIdx.y * 128;
    const int mwo = (w >> 1) * 64, nwo = (w & 1) * 64;
    const int r16 = lane & 15, quad = lane >> 4;
    const int kreg = quad * 8;
    const int K = 1024, N = 1024;

    f32x4 zero = {0.f, 0.f, 0.f, 0.f};
    f32x4 acc[4][4];
    #pragma unroll
    for (int i = 0; i < 4; ++i)
        #pragma unroll
        for (int j = 0; j < 4; ++j) acc[i][j] = zero;

    const int c0 = tid, c1 = tid + 256;
    const int am0 = c0 >> 2, ak0 = (c0 & 3) << 3;
    const int am1 = c1 >> 2, ak1 = (c1 & 3) << 3;

    {
        async_copy16(&sA[0][c0 * 8], &A[(size_t)(m0 + am0) * K + ak0]);
        async_copy16(&sA[0][c1 * 8], &A[(size_t)(m0 + am1) * K + ak1]);
        async_copy16(&sB[0][c0 * 8], &B[(size_t)(n0 + am0) * K + ak0]);
        async_copy16(&sB[0][c1 * 8], &B[(size_t)(n0 + am1) * K + ak1]);
    }
    for (int kt = 0; kt < 32; ++kt) {
        __syncthreads();
        const int cur = kt & 1, nxt = cur ^ 1;
        if (kt + 1 < 32) {
            const int kb = (kt + 1) << 5;
            async_copy16(&sA[nxt][c0 * 8], &A[(size_t)(m0 + am0) * K + kb + ak0]);
            async_copy16(&sA[nxt][c1 * 8], &A[(size_t)(m0 + am1) * K + kb + ak1]);
            async_copy16(&sB[nxt][c0 * 8], &B[(size_t)(n0 + am0) * K + kb + ak0]);
            async_copy16(&sB[nxt][c1 * 8], &B[(size_t)(n0 + am1) * K + kb + ak1]);
        }
        bf16x8 af[4], bfr[4];
        #pragma unroll
        for (int i = 0; i < 4; ++i) {
            af[i]  = *(const bf16x8*)&sA[cur][(mwo + i * 16 + r16) * 32 + kreg];
            bfr[i] = *(const bf16x8*)&sB[cur][(nwo + i * 16 + r16) * 32 + kreg];
        }
        #pragma unroll
        for (int mi = 0; mi < 4; ++mi)
            #pragma unroll
            for (int ni = 0; ni < 4; ++ni)
                acc[mi][ni] = __builtin_amdgcn_mfma_f32_16x16x32_bf16(af[mi], bfr[ni], acc[mi][ni], 0, 0, 0);
    }

    float bv[4];
    #pragma unroll
    for (int ni = 0; ni < 4; ++ni) bv[ni] = bias[n0 + nwo + ni * 16 + r16];

    if (z < 2) {
        bf16* C = (z == 0) ? C0 : C1;
        float nwv[4];
        #pragma unroll
        for (int ni = 0; ni < 4; ++ni) nwv[ni] = hw[ni * 16 + r16];
        #pragma unroll
        for (int mi = 0; mi < 4; ++mi) {
            #pragma unroll
            for (int r = 0; r < 4; ++r) {
                float v[4], ss = 0.0f;
                #pragma unroll
                for (int ni = 0; ni < 4; ++ni) {
                    v[ni] = clipf(acc[mi][ni][r] + bv[ni]);
                    ss += v[ni] * v[ni];
                }
                ss += __shfl_xor(ss, 1, 64);
                ss += __shfl_xor(ss, 2, 64);
                ss += __shfl_xor(ss, 4, 64);
                ss += __shfl_xor(ss, 8, 64);
                float rms = sqrtf(fmaxf(ss * (1.0f / 64.0f), EPS) + EPS);
                int row = m0 + mwo + mi * 16 + quad * 4 + r;
                #pragma unroll
                for (int ni = 0; ni < 4; ++ni) {
                    int col = n0 + nwo + ni * 16 + r16;
                    C[(size_t)row * N + col] = (bf16)fin0(v[ni] / rms * nwv[ni]);
                }
            }
        }
    } else {
        const int b_ = m0 >> 10;
        const int tokbase = (m0 & 1023) + mwo;
        #pragma unroll
        for (int ni = 0; ni < 4; ++ni) {
            int col = n0 + nwo + ni * 16 + r16;
            int h_ = col >> 6, hd = col & 63;
            bf16* dst = VT + (((size_t)b_ * 16 + h_) * 64 + hd) * 1024;
            #pragma unroll
            for (int mi = 0; mi < 4; ++mi) {
                bf16x4 pack;
                #pragma unroll
                for (int r = 0; r < 4; ++r) pack[r] = (bf16)(acc[mi][ni][r] + bv[ni]);
                *(bf16x4*)&dst[tokbase + mi * 16 + quad * 4] = pack;
            }
        }
    }
}

// ================= windowed causal flash attention, FIXED-MAX softmax (r9) =================
// grid: (L/64, H, B), block 256. q/k: (B,L,H,64); vt: (B,H,64,L).
__global__ __launch_bounds__(256) void attn_win(const bf16* __restrict__ q,
                                                const bf16* __restrict__ k,
                                                const bf16* __restrict__ vt,
                                                const int* __restrict__ winp,
                                                bf16* __restrict__ o) {
    __shared__ __align__(16) bf16 sQ[64 * 64];
    __shared__ __align__(16) bf16 sK[64 * 64];
    __shared__ __align__(16) bf16 sVt[64 * 80];
    __shared__ __align__(16) bf16 sP[64 * 64];
    const int tid = threadIdx.x, w = tid >> 6, lane = tid & 63;
    const int qt = blockIdx.x, h = blockIdx.y, b = blockIdx.z;
    const int q0 = qt * 64;
    const int win = *winp;
    const float scale = 0.125f;
    const int r16 = lane & 15, quad = lane >> 4;

    {
        int qr0 = tid >> 3, col0 = (tid & 7) * 8;
        async_copy16(&sQ[tid * 8], &q[(((size_t)b * 1024 + q0 + qr0) * 16 + h) * 64 + col0]);
        int c1 = tid + 256;
        int qr1 = c1 >> 3, col1 = (c1 & 7) * 8;
        async_copy16(&sQ[c1 * 8], &q[(((size_t)b * 1024 + q0 + qr1) * 16 + h) * 64 + col1]);
    }
    __syncthreads();
    bf16x8 aq0 = *(const bf16x8*)&sQ[(w * 16 + r16) * 64 + quad * 8];
    bf16x8 aq1 = *(const bf16x8*)&sQ[(w * 16 + r16) * 64 + 32 + quad * 8];

    float Lr[4];
    f32x4 zero = {0.f, 0.f, 0.f, 0.f};
    f32x4 accO[4];
    #pragma unroll
    for (int r = 0; r < 4; ++r) Lr[r] = 0.0f;
    #pragma unroll
    for (int nf = 0; nf < 4; ++nf) accO[nf] = zero;

    int lo = q0 - (win - 1); if (lo < 0) lo = 0;
    const int kt0 = lo >> 6;
    const bf16* vth = vt + ((size_t)b * 16 + h) * 64 * 1024;

    for (int kt = kt0; kt <= qt; ++kt) {
        __syncthreads();
        {
            int col0 = (tid & 7) * 8;
            async_copy16(&sK[tid * 8], &k[(((size_t)b * 1024 + kt * 64 + (tid >> 3)) * 16 + h) * 64 + col0]);
            int c1 = tid + 256;
            int col1 = (c1 & 7) * 8;
            async_copy16(&sK[c1 * 8], &k[(((size_t)b * 1024 + kt * 64 + (c1 >> 3)) * 16 + h) * 64 + col1]);
        }
        #pragma unroll
        for (int c = tid; c < 512; c += 256) {
            int hd = c >> 3, koff = (c & 7) * 8;
            *(u32x4*)&sVt[hd * 80 + koff] = *(const u32x4*)&vth[(size_t)hd * 1024 + kt * 64 + koff];
        }
        __syncthreads();

        f32x4 sf[4];
        #pragma unroll
        for (int nf = 0; nf < 4; ++nf) {
            bf16x8 bk0 = *(const bf16x8*)&sK[(nf * 16 + r16) * 64 + quad * 8];
            bf16x8 bk1 = *(const bf16x8*)&sK[(nf * 16 + r16) * 64 + 32 + quad * 8];
            f32x4 accS = zero;
            accS = __builtin_amdgcn_mfma_f32_16x16x32_bf16(aq0, bk0, accS, 0, 0, 0);
            accS = __builtin_amdgcn_mfma_f32_16x16x32_bf16(aq1, bk1, accS, 0, 0, 0);
            sf[nf] = accS;
        }

        #pragma unroll
        for (int r = 0; r < 4; ++r) {
            int i = q0 + w * 16 + quad * 4 + r;
            float ps = 0.0f;
            #pragma unroll
            for (int nf = 0; nf < 4; ++nf) {
                int j = kt * 64 + nf * 16 + r16;
                bool ok = (j <= i) && (i - j < win);
                float pv = ok ? __expf(sf[nf][r] * scale - 8.0f) : 0.0f;
                ps += pv;
                sP[(w * 16 + quad * 4 + r) * 64 + nf * 16 + r16] = (bf16)pv;
            }
            Lr[r] += ps;
        }
        __syncthreads();

        bf16x8 ap0 = *(const bf16x8*)&sP[(w * 16 + r16) * 64 + quad * 8];
        bf16x8 ap1 = *(const bf16x8*)&sP[(w * 16 + r16) * 64 + 32 + quad * 8];
        #pragma unroll
        for (int nf = 0; nf < 4; ++nf) {
            bf16x8 bv0 = *(const bf16x8*)&sVt[(nf * 16 + r16) * 80 + quad * 8];
            bf16x8 bv1 = *(const bf16x8*)&sVt[(nf * 16 + r16) * 80 + 32 + quad * 8];
            accO[nf] = __builtin_amdgcn_mfma_f32_16x16x32_bf16(ap0, bv0, accO[nf], 0, 0, 0);
            accO[nf] = __builtin_amdgcn_mfma_f32_16x16x32_bf16(ap1, bv1, accO[nf], 0, 0, 0);
        }
    }

    #pragma unroll
    for (int r = 0; r < 4; ++r) {
        float l = Lr[r];
        l += __shfl_xor(l, 1, 64);
        l += __shfl_xor(l, 2, 64);
        l += __shfl_xor(l, 4, 64);
        l += __shfl_xor(l, 8, 64);
        float inv = (l > 0.0f) ? 1.0f / l : 0.0f;
        int row = q0 + w * 16 + quad * 4 + r;
        #pragma unroll
        for (int nf = 0; nf < 4; ++nf) {
            float ov = fin0(accO[nf][r] * inv);
            o[(((size_t)b * 1024 + row) * 16 + h) * 64 + nf * 16 + r16] = (bf16)ov;
        }
    }
}

// ================= split-K=2 GEMM, 256x128 tile, 8 waves -> f32 partials =================
// P[s][M][1024] = A[M, s*Kh:(s+1)*Kh] @ B[1024, ...]^T. grid (M/256, 8, 2), block 512.
// Intensity: 24 KB staged -> 128 MFMA/iter = 5.33 MFMA/KB (2x the old 64x128 gemm_nk).
__global__ __launch_bounds__(512) void gemm_sk2(const bf16* __restrict__ A,
                                                const bf16* __restrict__ B,
                                                float* __restrict__ P,
                                                int K, int Kh) {
    __shared__ __align__(16) bf16 sA[2][256 * 32];   // 16 KB per buf
    __shared__ __align__(16) bf16 sB[2][128 * 32];   // 8 KB per buf
    const int tid = threadIdx.x;
    const int w = tid >> 6, lane = tid & 63;
    const int m0 = blockIdx.x * 256, n0 = blockIdx.y * 128;
    const int mwo = (w & 3) * 64, nwo = (w >> 2) * 64;   // 4 m-subs x 2 n-subs
    const int r16 = lane & 15, quad = lane >> 4, kreg = quad * 8;
    const int kbase = blockIdx.z * Kh;
    const int N = 1024;

    // A: 256 rows x 32 k = 1024 chunks of 16B; thread does chunk tid and tid+512.
    const int ar0 = tid >> 2,        ak0 = (tid & 3) << 3;
    const int c1 = tid + 512;
    const int ar1 = c1 >> 2,         ak1 = (c1 & 3) << 3;
    // B: 128 rows x 32 k = 512 chunks; thread does chunk tid.
    const int br = tid >> 2,         bk = (tid & 3) << 3;

    f32x4 zero = {0.f, 0.f, 0.f, 0.f};
    f32x4 acc[4][4];
    #pragma unroll
    for (int i = 0; i < 4; ++i)
        #pragma unroll
        for (int j = 0; j < 4; ++j) acc[i][j] = zero;

    {
        async_copy16(&sA[0][tid * 8], &A[(size_t)(m0 + ar0) * K + kbase + ak0]);
        async_copy16(&sA[0][c1 * 8],  &A[(size_t)(m0 + ar1) * K + kbase + ak1]);
        async_copy16(&sB[0][tid * 8], &B[(size_t)(n0 + br) * K + kbase + bk]);
    }
    const int kIters = Kh >> 5;
    for (int kt = 0; kt < kIters; ++kt) {
        __syncthreads();
        const int cur = kt & 1, nxt = cur ^ 1;
        if (kt + 1 < kIters) {
            const int kb = kbase + ((kt + 1) << 5);
            async_copy16(&sA[nxt][tid * 8], &A[(size_t)(m0 + ar0) * K + kb + ak0]);
            async_copy16(&sA[nxt][c1 * 8],  &A[(size_t)(m0 + ar1) * K + kb + ak1]);
            async_copy16(&sB[nxt][tid * 8], &B[(size_t)(n0 + br) * K + kb + bk]);
        }
        bf16x8 af[4], bfr[4];
        #pragma unroll
        for (int i = 0; i < 4; ++i) {
            af[i]  = *(const bf16x8*)&sA[cur][(mwo + i * 16 + r16) * 32 + kreg];
            bfr[i] = *(const bf16x8*)&sB[cur][(nwo + i * 16 + r16) * 32 + kreg];
        }
        #pragma unroll
        for (int mi = 0; mi < 4; ++mi)
            #pragma unroll
            for (int ni = 0; ni < 4; ++ni)
                acc[mi][ni] = __builtin_amdgcn_mfma_f32_16x16x32_bf16(af[mi], bfr[ni], acc[mi][ni], 0, 0, 0);
    }

    float* Pz = P + (size_t)blockIdx.z * 4096 * 1024;
    #pragma unroll
    for (int mi = 0; mi < 4; ++mi)
        #pragma unroll
        for (int ni = 0; ni < 4; ++ni) {
            int col = n0 + nwo + ni * 16 + r16;
            #pragma unroll
            for (int r = 0; r < 4; ++r) {
                int row = m0 + mwo + mi * 16 + quad * 4 + r;
                Pz[(size_t)row * N + col] = acc[mi][ni][r];
            }
        }
}

// ================= resid+norm (dual f32 partials): a = p0+p1+bias; h = x + rmsnorm(a, wpost);
// optional hn = rmsnorm(h, wnext). grid 512 x 512thr: 2 rows/block x 4 iters.
template <bool EMIT>
__global__ __launch_bounds__(512) void resid_norm(const float* __restrict__ xres,
                                                  const float* __restrict__ p0,
                                                  const float* __restrict__ p1,
                                                  const float* __restrict__ bias,
                                                  const float* __restrict__ wpost,
                                                  const float* __restrict__ wnext,
                                                  float* __restrict__ hout,
                                                  bf16* __restrict__ hnout) {
    __shared__ float sred[8];
    const int tid = threadIdx.x;
    const int grp = tid >> 8, t = tid & 255;
    const int w4 = (tid >> 6) & 3;
    for (int it = 0; it < 4; ++it) {
        int row = it * 1024 + blockIdx.x * 2 + grp;
        f32x4 a0 = ((const f32x4*)(p0 + (size_t)row * 1024))[t];
        f32x4 a1 = ((const f32x4*)(p1 + (size_t)row * 1024))[t];
        f32x4 bv = ((const f32x4*)bias)[t];
        f32x4 af;
        af[0] = clipf(a0[0] + a1[0] + bv[0]);
        af[1] = clipf(a0[1] + a1[1] + bv[1]);
        af[2] = clipf(a0[2] + a1[2] + bv[2]);
        af[3] = clipf(a0[3] + a1[3] + bv[3]);
        float ss = af[0]*af[0] + af[1]*af[1] + af[2]*af[2] + af[3]*af[3];
        #pragma unroll
        for (int off = 32; off >= 1; off >>= 1) ss += __shfl_xor(ss, off, 64);
        __syncthreads();
        if ((tid & 63) == 0) sred[grp * 4 + w4] = ss;
        __syncthreads();
        float tot = sred[grp*4+0] + sred[grp*4+1] + sred[grp*4+2] + sred[grp*4+3];
        float rms1 = sqrtf(fmaxf(tot * (1.0f / 1024.0f), EPS) + EPS);
        f32x4 xv = ((const f32x4*)(xres + (size_t)row * 1024))[t];
        f32x4 wp = ((const f32x4*)wpost)[t];
        f32x4 hv;
        hv[0] = xv[0] + fin0(af[0] / rms1 * wp[0]);
        hv[1] = xv[1] + fin0(af[1] / rms1 * wp[1]);
        hv[2] = xv[2] + fin0(af[2] / rms1 * wp[2]);
        hv[3] = xv[3] + fin0(af[3] / rms1 * wp[3]);
        ((f32x4*)(hout + (size_t)row * 1024))[t] = hv;
        if (EMIT) {
            f32x4 cv;
            cv[0] = clipf(hv[0]); cv[1] = clipf(hv[1]); cv[2] = clipf(hv[2]); cv[3] = clipf(hv[3]);
            float ss2 = cv[0]*cv[0] + cv[1]*cv[1] + cv[2]*cv[2] + cv[3]*cv[3];
            #pragma unroll
            for (int off = 32; off >= 1; off >>= 1) ss2 += __shfl_xor(ss2, off, 64);
            __syncthreads();
            if ((tid & 63) == 0) sred[grp * 4 + w4] = ss2;
            __syncthreads();
            float tot2 = sred[grp*4+0] + sred[grp*4+1] + sred[grp*4+2] + sred[grp*4+3];
            float rms2 = sqrtf(fmaxf(tot2 * (1.0f / 1024.0f), EPS) + EPS);
            f32x4 wn = ((const f32x4*)wnext)[t];
            bf16x4 o;
            o[0] = (bf16)fin0(cv[0] / rms2 * wn[0]);
            o[1] = (bf16)fin0(cv[1] / rms2 * wn[1]);
            o[2] = (bf16)fin0(cv[2] / rms2 * wn[2]);
            o[3] = (bf16)fin0(cv[3] / rms2 * wn[3]);
            *(bf16x4*)(hnout + (size_t)row * 1024 + t * 4) = o;
        }
    }
}

// ================= fused FFN1 (r7-best, 128x128, dbuf): g = silu(A@W1^T+b1)*(A@W3^T+b3) =======
// grid (32, 26), block 512 (8 waves, 64x32 per stream per wave).
__global__ __launch_bounds__(512) void gemm_ffn1(const bf16* __restrict__ A,
                                                 const bf16* __restrict__ B1,
                                                 const bf16* __restrict__ B3,
                                                 const float* __restrict__ b1,
                                                 const float* __restrict__ b3,
                                                 bf16* __restrict__ G) {
    __shared__ __align__(16) bf16 sA[2][128 * 32];
    __shared__ __align__(16) bf16 sB1[2][128 * 32];
    __shared__ __align__(16) bf16 sB3[2][128 * 32];
    const int tid = threadIdx.x;
    const int w = tid >> 6, lane = tid & 63;
    const int m0 = blockIdx.x * 128;
    const int n0 = blockIdx.y * 128;
    const int mwo = (w >> 2) * 64, nwo = (w & 3) * 32;
    const int r16 = lane & 15, quad = lane >> 4;
    const int kreg = quad * 8;
    const int K = 1024, N = 3328;

    f32x4 zero = {0.f, 0.f, 0.f, 0.f};
    f32x4 acc1[4][2], acc3[4][2];
    #pragma unroll
    for (int i = 0; i < 4; ++i)
        #pragma unroll
        for (int j = 0; j < 2; ++j) { acc1[i][j] = zero; acc3[i][j] = zero; }

    const int arow = tid >> 2, akoff = (tid & 3) << 3;

    {
        async_copy16(&sA[0][tid * 8],  &A[(size_t)(m0 + arow) * K + akoff]);
        async_copy16(&sB1[0][tid * 8], &B1[(size_t)(n0 + arow) * K + akoff]);
        async_copy16(&sB3[0][tid * 8], &B3[(size_t)(n0 + arow) * K + akoff]);
    }
    for (int kt = 0; kt < 32; ++kt) {
        __syncthreads();
        const int cur = kt & 1, nxt = cur ^ 1;
        if (kt + 1 < 32) {
            const int kb = (kt + 1) << 5;
            async_copy16(&sA[nxt][tid * 8],  &A[(size_t)(m0 + arow) * K + kb + akoff]);
            async_copy16(&sB1[nxt][tid * 8], &B1[(size_t)(n0 + arow) * K + kb + akoff]);
            async_copy16(&sB3[nxt][tid * 8], &B3[(size_t)(n0 + arow) * K + kb + akoff]);
        }
        bf16x8 af[4], bf1[2], bf3[2];
        #pragma unroll
        for (int i = 0; i < 4; ++i)
            af[i]  = *(const bf16x8*)&sA[cur][(mwo + i * 16 + r16) * 32 + kreg];
        #pragma unroll
        for (int i = 0; i < 2; ++i) {
            bf1[i] = *(const bf16x8*)&sB1[cur][(nwo + i * 16 + r16) * 32 + kreg];
            bf3[i] = *(const bf16x8*)&sB3[cur][(nwo + i * 16 + r16) * 32 + kreg];
        }
        #pragma unroll
        for (int mi = 0; mi < 4; ++mi)
            #pragma unroll
            for (int ni = 0; ni < 2; ++ni) {
                acc1[mi][ni] = __builtin_amdgcn_mfma_f32_16x16x32_bf16(af[mi], bf1[ni], acc1[mi][ni], 0, 0, 0);
                acc3[mi][ni] = __builtin_amdgcn_mfma_f32_16x16x32_bf16(af[mi], bf3[ni], acc3[mi][ni], 0, 0, 0);
            }
    }

    #pragma unroll
    for (int ni = 0; ni < 2; ++ni) {
        int col = n0 + nwo + ni * 16 + r16;
        float bv1 = (col < 3280) ? b1[col] : 0.0f;
        float bv3 = (col < 3280) ? b3[col] : 0.0f;
        #pragma unroll
        for (int mi = 0; mi < 4; ++mi) {
            #pragma unroll
            for (int r = 0; r < 4; ++r) {
                int row = m0 + mwo + mi * 16 + quad * 4 + r;
                float z1 = acc1[mi][ni][r] + bv1;
                float z3 = acc3[mi][ni][r] + bv3;
                float s = z1 / (1.0f + __expf(-z1));
                G[(size_t)row * N + col] = (bf16)(s * z3);
            }
        }
    }
}

extern "C" void kernel_launch(void* const* d_in, const int* in_sizes, int n_in,
                              void* d_out, int out_size, void* d_ws, size_t ws_size,
                              hipStream_t stream) {
    const float* x       = (const float*)d_in[0];
    const float* wq_w    = (const float*)d_in[1];
    const float* wq_b    = (const float*)d_in[2];
    const float* wk_w    = (const float*)d_in[3];
    const float* wk_b    = (const float*)d_in[4];
    const float* wv_w    = (const float*)d_in[5];
    const float* wv_b    = (const float*)d_in[6];
    const float* wo_w    = (const float*)d_in[7];
    const float* wo_b    = (const float*)d_in[8];
    const float* q_norm_w= (const float*)d_in[9];
    const float* k_norm_w= (const float*)d_in[10];
    const float* seq_norm_w      = (const float*)d_in[11];
    const float* seq_post_norm_w = (const float*)d_in[12];
    const float* ffn_norm_w      = (const float*)d_in[13];
    const float* ffn_post_norm_w = (const float*)d_in[14];
    const float* w1_w    = (const float*)d_in[15];
    const float* w1_b    = (const float*)d_in[16];
    const float* w2_w    = (const float*)d_in[17];
    const float* w2_b    = (const float*)d_in[18];
    const float* w3_w    = (const float*)d_in[19];
    const float* w3_b    = (const float*)d_in[20];
    const int*   winp    = (const int*)d_in[21];
    float* out = (float*)d_out;

    const size_t SZ_W   = 2097152;    // 1024*1024*2
    const size_t SZ_WP  = 6815744;    // 3328*1024*2
    const size_t SZ_ACT = 8388608;    // 4096*1024*2
    const size_t SZ_H   = 16777216;   // 4096*1024*4
    const size_t SZ_P   = 33554432;   // 2*4096*1024*4 (split-K partials)

    char* p = (char*)d_ws;
    bf16* Wq  = (bf16*)p; p += SZ_W;
    bf16* Wk  = (bf16*)p; p += SZ_W;
    bf16* Wv  = (bf16*)p; p += SZ_W;
    bf16* Wo  = (bf16*)p; p += SZ_W;
    bf16* W1p = (bf16*)p; p += SZ_WP;
    bf16* W3p = (bf16*)p; p += SZ_WP;
    bf16* W2p = (bf16*)p; p += SZ_WP;
    float* h  = (float*)p; p += SZ_H;
    bf16* hn  = (bf16*)p; p += SZ_ACT;
    float* part = (float*)p; p += SZ_P;
    float* part1 = part + (size_t)4096 * 1024;
    char* regionA = p;  // aliased: attn-phase buffers, later g
    bf16* xn    = (bf16*)(regionA);
    bf16* qb    = (bf16*)(regionA + 1 * SZ_ACT);
    bf16* kb    = (bf16*)(regionA + 2 * SZ_ACT);
    bf16* vtb   = (bf16*)(regionA + 3 * SZ_ACT);
    bf16* attnb = (bf16*)(regionA + 4 * SZ_ACT);
    bf16* g     = (bf16*)(regionA);   // 27.3 MB; reuses xn..vtb after attention phase

    // 1) prep: all converts + rmsnorm(x)
    prep<<<dim3(15872), dim3(256), 0, stream>>>(wq_w, wk_w, wv_w, wo_w, Wq, Wk, Wv, Wo,
                                                w1_w, w3_w, W1p, W3p, w2_w, W2p,
                                                x, seq_norm_w, xn);

    // 2) QKV projections; q,k head-normed; v transposed
    gemm_qkv<<<dim3(32, 8, 3), dim3(256), 0, stream>>>(xn, Wq, Wk, Wv, wq_b, wk_b, wv_b,
                                                       q_norm_w, k_norm_w, qb, kb, vtb);

    // 3) windowed causal attention (fixed-max softmax)
    attn_win<<<dim3(16, 16, 4), dim3(256), 0, stream>>>(qb, kb, vtb, winp, attnb);

    // 4) O-projection: 256x128 split-K=2 -> f32 partials (K=1024, Kh=512)
    gemm_sk2<<<dim3(16, 8, 2), dim3(512), 0, stream>>>(attnb, Wo, part, 1024, 512);

    // 5) h = x + rmsnorm(p0+p1+wo_b, seq_post); hn = rmsnorm(h, ffn_norm)
    resid_norm<true><<<dim3(512), dim3(512), 0, stream>>>(x, part, part1, wo_b,
                                                          seq_post_norm_w, ffn_norm_w, h, hn);

    // 6) fused FFN1, 128x128 tiles (r7-best)
    gemm_ffn1<<<dim3(32, 26), dim3(512), 0, stream>>>(hn, W1p, W3p, w1_b, w3_b, g);

    // 7) FFN2: 256x128 split-K=2 -> f32 partials (K=3328, Kh=1664, 52 iters)
    gemm_sk2<<<dim3(16, 8, 2), dim3(512), 0, stream>>>(g, W2p, part, 3328, 1664);

    // 8) out = h + rmsnorm(p0+p1+w2_b, ffn_post)
    resid_norm<false><<<dim3(512), dim3(512), 0, stream>>>(h, part, part1, w2_b,
                                                           ffn_post_norm_w, nullptr, out, nullptr);
}